// Round 1
// baseline (624.356 us; speedup 1.0000x reference)
//
#include <hip/hip_runtime.h>
#include <hip/hip_bf16.h>
#include <math.h>

#define EPS 1e-5f
#define MAXN (1.0f - EPS)
#define MINN 1e-10f

constexpr int D = 2048;      // Dh == Din == 2048 for this problem
constexpr int LPT = 8;       // elements per thread in row kernels (D / 256)

typedef unsigned short u16;
typedef __bf16 bf16x8 __attribute__((ext_vector_type(8)));
typedef float floatx4 __attribute__((ext_vector_type(4)));

// ---------- small helpers ----------

__device__ __forceinline__ u16 f2bf(float f) {
    union { float f; unsigned u; } v; v.f = f;
    unsigned r = v.u + 0x7FFFu + ((v.u >> 16) & 1u);   // RNE
    return (u16)(r >> 16);
}

__device__ __forceinline__ float artanh_(float x) {
    x = fminf(fmaxf(x, -1.0f + EPS), 1.0f - EPS);
    return 0.5f * logf((1.0f + x) / (1.0f - x));
}

__device__ __forceinline__ float sigmoid_(float x) {
    return 1.0f / (1.0f + expf(-x));
}

// all 256 threads must call; 4 waves assumed
__device__ __forceinline__ float block_sum(float v, float* sbuf) {
    #pragma unroll
    for (int off = 32; off >= 1; off >>= 1) v += __shfl_xor(v, off, 64);
    int w = threadIdx.x >> 6;
    __syncthreads();                       // protect sbuf from previous call
    if ((threadIdx.x & 63) == 0) sbuf[w] = v;
    __syncthreads();
    return sbuf[0] + sbuf[1] + sbuf[2] + sbuf[3];
}

// finish mob_mat_mul: given |Mx|^2 and g = artanh(x_n)/x_n, return scale coef
// (out = coef * Mx_raw) and the output norm (post-proj).
__device__ __forceinline__ void mmm_finish(float sum2, float g, float* coef, float* onorm) {
    float mxn = sqrtf(fmaxf(sum2, MINN));
    float tt  = tanhf(mxn * g);
    float on  = fminf(tt, MAXN);
    *coef = on / mxn;
    *onorm = on;
}

// u <- proj(mob_add(u, v)); u2 = |u|^2, v2 = |v|^2. Returns post-proj norm.
__device__ __forceinline__ float mob_add_frag(float* u, const float* v,
                                              float u2, float v2, float* sbuf) {
    float duv = 0.f;
    #pragma unroll
    for (int i = 0; i < LPT; ++i) duv += u[i] * v[i];
    duv = block_sum(duv, sbuf);
    float cu  = 1.f + 2.f * duv + v2;
    float cv  = 1.f - u2;
    float den = fmaxf(1.f + 2.f * duv + u2 * v2, MINN);
    float s2 = 0.f;
    #pragma unroll
    for (int i = 0; i < LPT; ++i) {
        float nm = cu * u[i] + cv * v[i];
        u[i] = nm;
        s2 += nm * nm;
    }
    s2 = block_sum(s2, sbuf);
    float n  = sqrtf(fmaxf(s2 / (den * den), MINN));
    float sc = ((n > MAXN) ? MAXN / n : 1.f) / den;
    #pragma unroll
    for (int i = 0; i < LPT; ++i) u[i] *= sc;
    return fminf(n, MAXN);
}

// ---------- K0: weight f32 [K,N] -> bf16 transposed [N,K] ----------

struct TransBatch { const float* W[5]; u16* Wt[5]; };

__global__ __launch_bounds__(256) void wtrans(TransBatch tb) {
    const float* W = tb.W[blockIdx.z];
    u16* Wt = tb.Wt[blockIdx.z];
    __shared__ float tile[32][33];
    int n0 = blockIdx.x * 32, k0 = blockIdx.y * 32;
    int tc = threadIdx.x & 31, tr = threadIdx.x >> 5;   // tr in 0..7
    #pragma unroll
    for (int i = 0; i < 4; ++i) {
        int r = tr + i * 8;
        tile[r][tc] = W[(size_t)(k0 + r) * D + n0 + tc];
    }
    __syncthreads();
    #pragma unroll
    for (int i = 0; i < 4; ++i) {
        int r = tr + i * 8;
        Wt[(size_t)(n0 + r) * D + k0 + tc] = f2bf(tile[tc][r]);
    }
}

// ---------- K1: project inputs, emit bf16 copies + g scalars ----------

__global__ __launch_bounds__(256) void prep(
    const float* __restrict__ hx, const float* __restrict__ h,
    u16* __restrict__ hx_bf, u16* __restrict__ h_bf,
    float* __restrict__ h_proj, float* __restrict__ g_x, float* __restrict__ g_h) {
    __shared__ float sbuf[4];
    int b = blockIdx.x, t = threadIdx.x;
    size_t off = (size_t)b * D;

    // hyp_x row
    {
        float xv[LPT]; float s = 0.f;
        #pragma unroll
        for (int i = 0; i < LPT; ++i) { xv[i] = hx[off + t + 256 * i]; s += xv[i] * xv[i]; }
        float n = sqrtf(fmaxf(block_sum(s, sbuf), MINN));
        float scale = (n > MAXN) ? MAXN / n : 1.0f;
        float xn = fminf(n, MAXN);
        #pragma unroll
        for (int i = 0; i < LPT; ++i) hx_bf[off + t + 256 * i] = f2bf(xv[i] * scale);
        if (t == 0) g_x[b] = artanh_(xn) / xn;
    }
    // hidden row
    {
        float xv[LPT]; float s = 0.f;
        #pragma unroll
        for (int i = 0; i < LPT; ++i) { xv[i] = h[off + t + 256 * i]; s += xv[i] * xv[i]; }
        float n = sqrtf(fmaxf(block_sum(s, sbuf), MINN));
        float scale = (n > MAXN) ? MAXN / n : 1.0f;
        float xn = fminf(n, MAXN);
        #pragma unroll
        for (int i = 0; i < LPT; ++i) {
            float pv = xv[i] * scale;
            h_bf[off + t + 256 * i] = f2bf(pv);
            h_proj[off + t + 256 * i] = pv;
        }
        if (t == 0) g_h[b] = artanh_(xn) / xn;
    }
}

// ---------- GEMM: C[M,N] = A[M,K](bf16) @ Wt[N,K](bf16)^T, fp32 out ----------

struct GemmBatch { const u16* A[4]; const u16* W[4]; float* C[4]; };

__global__ __launch_bounds__(256) void gemm_bt(GemmBatch gb, int M) {
    int z = blockIdx.z;
    const u16* __restrict__ A = gb.A[z];
    const u16* __restrict__ W = gb.W[z];
    float* __restrict__ C = gb.C[z];

    __shared__ u16 As[128 * 40];   // 128 rows x 32 k, stride 40 (pad)
    __shared__ u16 Ws[128 * 40];

    int t = threadIdx.x;
    int wave = t >> 6, lane = t & 63;
    int wr = wave >> 1, wc = wave & 1;       // 2x2 wave grid, each 64x64
    int quad = lane >> 4, l16 = lane & 15;
    int brow = blockIdx.y * 128, bcol = blockIdx.x * 128;

    floatx4 acc[4][4];
    #pragma unroll
    for (int i = 0; i < 4; ++i)
        #pragma unroll
        for (int j = 0; j < 4; ++j)
            #pragma unroll
            for (int e = 0; e < 4; ++e) acc[i][j][e] = 0.f;

    for (int k0 = 0; k0 < D; k0 += 32) {
        uint4 va[2], vw[2];
        #pragma unroll
        for (int i = 0; i < 2; ++i) {
            int li = t + 256 * i;
            int row = li >> 2, seg = li & 3;
            va[i] = *(const uint4*)(A + (size_t)(brow + row) * D + k0 + seg * 8);
            vw[i] = *(const uint4*)(W + (size_t)(bcol + row) * D + k0 + seg * 8);
        }
        __syncthreads();     // previous iteration's ds_reads complete
        #pragma unroll
        for (int i = 0; i < 2; ++i) {
            int li = t + 256 * i;
            int row = li >> 2, seg = li & 3;
            *(uint4*)(&As[row * 40 + seg * 8]) = va[i];
            *(uint4*)(&Ws[row * 40 + seg * 8]) = vw[i];
        }
        __syncthreads();

        bf16x8 af[4], bfv[4];
        #pragma unroll
        for (int i = 0; i < 4; ++i)
            af[i] = *(const bf16x8*)(&As[(wr * 64 + i * 16 + l16) * 40 + quad * 8]);
        #pragma unroll
        for (int j = 0; j < 4; ++j)
            bfv[j] = *(const bf16x8*)(&Ws[(wc * 64 + j * 16 + l16) * 40 + quad * 8]);
        #pragma unroll
        for (int i = 0; i < 4; ++i)
            #pragma unroll
            for (int j = 0; j < 4; ++j)
                acc[i][j] = __builtin_amdgcn_mfma_f32_16x16x32_bf16(af[i], bfv[j], acc[i][j], 0, 0, 0);
    }

    #pragma unroll
    for (int i = 0; i < 4; ++i) {
        #pragma unroll
        for (int j = 0; j < 4; ++j) {
            int row = brow + wr * 64 + i * 16 + quad * 4;
            int col = bcol + wc * 64 + j * 16 + l16;
            #pragma unroll
            for (int r = 0; r < 4; ++r)
                C[(size_t)(row + r) * D + col] = acc[i][j][r];
        }
    }
}

// ---------- K4: fused middle (finish 4 matvecs, z, r, r_point_h) ----------

__global__ __launch_bounds__(256) void mid_kernel(
    const float* __restrict__ c_wz, const float* __restrict__ c_uz,
    const float* __restrict__ c_wr, const float* __restrict__ c_ur,
    const float* __restrict__ h_proj,
    const float* __restrict__ g_x, const float* __restrict__ g_h,
    const float* __restrict__ b_z, const float* __restrict__ b_r,
    float* __restrict__ z_out, float* __restrict__ uxr_out,
    u16* __restrict__ rph_bf, float* __restrict__ g_rph) {
    __shared__ float sbuf[4];
    int b = blockIdx.x, t = threadIdx.x;
    size_t off = (size_t)b * D;

    float wz[LPT], uz[LPT], wr2[LPT], ur2[LPT], hp[LPT], bz[LPT], br[LPT], zz[LPT];
    float swz = 0, suz = 0, swr = 0, sur = 0;
    #pragma unroll
    for (int i = 0; i < LPT; ++i) {
        int c = t + 256 * i;
        wz[i]  = c_wz[off + c];  swz += wz[i] * wz[i];
        uz[i]  = c_uz[off + c];  suz += uz[i] * uz[i];
        wr2[i] = c_wr[off + c];  swr += wr2[i] * wr2[i];
        ur2[i] = c_ur[off + c];  sur += ur2[i] * ur2[i];
        hp[i]  = h_proj[off + c];
        bz[i]  = b_z[c];
        br[i]  = b_r[c];
    }
    float gh = g_h[b], gx = g_x[b];
    swz = block_sum(swz, sbuf);
    suz = block_sum(suz, sbuf);
    swr = block_sum(swr, sbuf);
    sur = block_sum(sur, sbuf);

    float cwz, nwz, cuz, nuz, cwr, nwr, cur, nur;
    mmm_finish(swz, gh, &cwz, &nwz);
    mmm_finish(suz, gx, &cuz, &nuz);
    mmm_finish(swr, gh, &cwr, &nwr);
    mmm_finish(sur, gx, &cur, &nur);
    #pragma unroll
    for (int i = 0; i < LPT; ++i) {
        wz[i] *= cwz; uz[i] *= cuz; wr2[i] *= cwr; ur2[i] *= cur;
    }

    // |b|^2 reductions
    float sbz = 0, sbr2 = 0;
    #pragma unroll
    for (int i = 0; i < LPT; ++i) { sbz += bz[i] * bz[i]; sbr2 += br[i] * br[i]; }
    sbz  = block_sum(sbz, sbuf);
    sbr2 = block_sum(sbr2, sbuf);

    // z chain
    float n1 = mob_add_frag(wz, uz, nwz * nwz, nuz * nuz, sbuf);
    float n2 = mob_add_frag(wz, bz, n1 * n1, sbz, sbuf);
    float gz = artanh_(n2) / n2;
    #pragma unroll
    for (int i = 0; i < LPT; ++i) {
        zz[i] = sigmoid_(gz * wz[i]);
        z_out[off + t + 256 * i] = zz[i];
    }

    // r chain
    float n1r = mob_add_frag(wr2, ur2, nwr * nwr, nur * nur, sbuf);
    float n2r = mob_add_frag(wr2, br, n1r * n1r, sbr2, sbuf);
    float gr = artanh_(n2r) / n2r;
    #pragma unroll
    for (int i = 0; i < LPT; ++i) br[i] = sigmoid_(gr * wr2[i]);   // br := r

    // r_point_h = exp_map_zero(log_map_zero(h_proj) * r)
    float sv = 0.f;
    #pragma unroll
    for (int i = 0; i < LPT; ++i) {
        float v = gh * hp[i] * br[i];
        wz[i] = v;                 // reuse wz as v
        sv += v * v;
    }
    sv = block_sum(sv, sbuf);
    float nv = sqrtf(fmaxf(sv, MINN));
    float th = fminf(tanhf(nv), MAXN);
    float cr = th / nv;
    #pragma unroll
    for (int i = 0; i < LPT; ++i) {
        rph_bf[off + t + 256 * i] = f2bf(wz[i] * cr);
        uxr_out[off + t + 256 * i] = ur2[i];   // finished UxR (reused for h_tilde)
    }
    if (t == 0) g_rph[b] = artanh_(th) / th;
}

// ---------- K6: epilogue ----------

__global__ __launch_bounds__(256) void fin_kernel(
    const float* __restrict__ c_wh, const float* __restrict__ uxr,
    const float* __restrict__ z_in, const float* __restrict__ h_proj,
    const float* __restrict__ g_rph, const float* __restrict__ b_h,
    float* __restrict__ out) {
    __shared__ float sbuf[4];
    int b = blockIdx.x, t = threadIdx.x;
    size_t off = (size_t)b * D;

    float wh[LPT], ux[LPT], zz[LPT], hp[LPT], bh[LPT];
    float swh = 0, sux = 0, shp = 0, sbh = 0;
    #pragma unroll
    for (int i = 0; i < LPT; ++i) {
        int c = t + 256 * i;
        wh[i] = c_wh[off + c];  swh += wh[i] * wh[i];
        ux[i] = uxr[off + c];   sux += ux[i] * ux[i];
        zz[i] = z_in[off + c];
        hp[i] = h_proj[off + c]; shp += hp[i] * hp[i];
        bh[i] = b_h[c];         sbh += bh[i] * bh[i];
    }
    swh = block_sum(swh, sbuf);
    sux = block_sum(sux, sbuf);
    shp = block_sum(shp, sbuf);
    sbh = block_sum(sbh, sbuf);

    float cwh, nwh;
    mmm_finish(swh, g_rph[b], &cwh, &nwh);
    #pragma unroll
    for (int i = 0; i < LPT; ++i) wh[i] *= cwh;

    // h_tilde = mob_add(mob_add(WhH, UxR), b_h)
    float n1  = mob_add_frag(wh, ux, nwh * nwh, sux, sbuf);
    float nht = mob_add_frag(wh, bh, n1 * n1, sbh, sbuf);

    // minus = mob_add(-h_proj, h_tilde)
    #pragma unroll
    for (int i = 0; i < LPT; ++i) ux[i] = -hp[i];   // reuse ux
    float nm = mob_add_frag(ux, wh, shp, nht * nht, sbuf);

    // emz = exp_map_zero(log_map_zero(minus) * z)
    float lm = artanh_(nm) / nm;
    float sv = 0.f;
    #pragma unroll
    for (int i = 0; i < LPT; ++i) {
        float v = lm * ux[i] * zz[i];
        ux[i] = v;
        sv += v * v;
    }
    sv = block_sum(sv, sbuf);
    float nv = sqrtf(fmaxf(sv, MINN));
    float th = fminf(tanhf(nv), MAXN);
    float ce = th / nv;
    #pragma unroll
    for (int i = 0; i < LPT; ++i) ux[i] *= ce;

    // new_h = mob_add(h_proj, emz)
    mob_add_frag(hp, ux, shp, th * th, sbuf);
    #pragma unroll
    for (int i = 0; i < LPT; ++i) out[off + t + 256 * i] = hp[i];
}

// ---------- launch ----------

extern "C" void kernel_launch(void* const* d_in, const int* in_sizes, int n_in,
                              void* d_out, int out_size, void* d_ws, size_t ws_size,
                              hipStream_t stream) {
    const float* hyp_x  = (const float*)d_in[0];
    const float* hidden = (const float*)d_in[1];
    const float* w_z = (const float*)d_in[2];
    const float* w_r = (const float*)d_in[3];
    const float* w_h = (const float*)d_in[4];
    const float* u_z = (const float*)d_in[5];
    const float* u_r = (const float*)d_in[6];
    const float* b_z = (const float*)d_in[7];
    const float* b_r = (const float*)d_in[8];
    const float* b_h = (const float*)d_in[9];
    float* out = (float*)d_out;

    int B = in_sizes[1] / D;   // 2048

    char* ws = (char*)d_ws;
    size_t o = 0;
    auto alloc = [&](size_t bytes) -> void* {
        void* p = ws + o;
        o += (bytes + 255) & ~(size_t)255;
        return p;
    };
    u16* wt[5];
    for (int i = 0; i < 5; ++i) wt[i] = (u16*)alloc((size_t)D * D * 2);
    u16* hx_bf   = (u16*)alloc((size_t)B * D * 2);
    u16* h_bf    = (u16*)alloc((size_t)B * D * 2);
    float* h_proj = (float*)alloc((size_t)B * D * 4);
    float* g_x   = (float*)alloc((size_t)B * 4);
    float* g_h   = (float*)alloc((size_t)B * 4);
    float* g_rph = (float*)alloc((size_t)B * 4);
    float* c0 = (float*)alloc((size_t)B * D * 4);
    float* c1 = (float*)alloc((size_t)B * D * 4);
    float* c2 = (float*)alloc((size_t)B * D * 4);
    float* c3 = (float*)alloc((size_t)B * D * 4);
    float* z_buf = (float*)alloc((size_t)B * D * 4);
    float* uxr   = (float*)alloc((size_t)B * D * 4);
    u16* rph     = (u16*)alloc((size_t)B * D * 2);

    // K0: transpose+convert 5 weight matrices (order: w_z,w_r,w_h,u_z,u_r)
    TransBatch tb;
    tb.W[0] = w_z; tb.W[1] = w_r; tb.W[2] = w_h; tb.W[3] = u_z; tb.W[4] = u_r;
    for (int i = 0; i < 5; ++i) tb.Wt[i] = wt[i];
    wtrans<<<dim3(D / 32, D / 32, 5), 256, 0, stream>>>(tb);

    // K1: projections
    prep<<<dim3(B), 256, 0, stream>>>(hyp_x, hidden, hx_bf, h_bf, h_proj, g_x, g_h);

    // G1: c0 = h@w_z, c1 = x@u_z, c2 = h@w_r, c3 = x@u_r
    GemmBatch g1;
    g1.A[0] = h_bf;  g1.W[0] = wt[0]; g1.C[0] = c0;
    g1.A[1] = hx_bf; g1.W[1] = wt[3]; g1.C[1] = c1;
    g1.A[2] = h_bf;  g1.W[2] = wt[1]; g1.C[2] = c2;
    g1.A[3] = hx_bf; g1.W[3] = wt[4]; g1.C[3] = c3;
    gemm_bt<<<dim3(D / 128, B / 128, 4), 256, 0, stream>>>(g1, B);

    // K4: middle fusion
    mid_kernel<<<dim3(B), 256, 0, stream>>>(c0, c1, c2, c3, h_proj, g_x, g_h,
                                            b_z, b_r, z_buf, uxr, rph, g_rph);

    // G2: c0 = r_point_h @ w_h  (reuse c0 slot)
    GemmBatch g2;
    g2.A[0] = rph; g2.W[0] = wt[2]; g2.C[0] = c0;
    g2.A[1] = rph; g2.W[1] = wt[2]; g2.C[1] = c0;
    g2.A[2] = rph; g2.W[2] = wt[2]; g2.C[2] = c0;
    g2.A[3] = rph; g2.W[3] = wt[2]; g2.C[3] = c0;
    gemm_bt<<<dim3(D / 128, B / 128, 1), 256, 0, stream>>>(g2, B);

    // K6: epilogue
    fin_kernel<<<dim3(B), 256, 0, stream>>>(c0, uxr, z_buf, h_proj, g_rph, b_h, out);
}

// Round 2
// 349.447 us; speedup vs baseline: 1.7867x; 1.7867x over previous
//
#include <hip/hip_runtime.h>
#include <hip/hip_bf16.h>
#include <math.h>

#define EPS 1e-5f
#define MAXN (1.0f - EPS)
#define MINN 1e-10f

constexpr int D = 2048;      // Dh == Din == 2048 for this problem
constexpr int LPT = 8;       // elements per thread in row kernels (D / 256)

typedef unsigned short u16;
typedef __bf16 bf16x8 __attribute__((ext_vector_type(8)));
typedef float floatx4 __attribute__((ext_vector_type(4)));

// ---------- small helpers ----------

__device__ __forceinline__ u16 f2bf(float f) {
    union { float f; unsigned u; } v; v.f = f;
    unsigned r = v.u + 0x7FFFu + ((v.u >> 16) & 1u);   // RNE
    return (u16)(r >> 16);
}

__device__ __forceinline__ float artanh_(float x) {
    x = fminf(fmaxf(x, -1.0f + EPS), 1.0f - EPS);
    return 0.5f * logf((1.0f + x) / (1.0f - x));
}

__device__ __forceinline__ float sigmoid_(float x) {
    return 1.0f / (1.0f + expf(-x));
}

// async global->LDS, 16 bytes/lane; lds base must be wave-uniform
__device__ __forceinline__ void gl_lds16(const u16* g, u16* l) {
    __builtin_amdgcn_global_load_lds(
        (const __attribute__((address_space(1))) unsigned int*)g,
        (__attribute__((address_space(3))) unsigned int*)l, 16, 0, 0);
}

// all 256 threads must call; 4 waves assumed
__device__ __forceinline__ float block_sum(float v, float* sbuf) {
    #pragma unroll
    for (int off = 32; off >= 1; off >>= 1) v += __shfl_xor(v, off, 64);
    int w = threadIdx.x >> 6;
    __syncthreads();                       // protect sbuf from previous call
    if ((threadIdx.x & 63) == 0) sbuf[w] = v;
    __syncthreads();
    return sbuf[0] + sbuf[1] + sbuf[2] + sbuf[3];
}

// finish mob_mat_mul: given |Mx|^2 and g = artanh(x_n)/x_n, return scale coef
// (out = coef * Mx_raw) and the output norm (post-proj).
__device__ __forceinline__ void mmm_finish(float sum2, float g, float* coef, float* onorm) {
    float mxn = sqrtf(fmaxf(sum2, MINN));
    float tt  = tanhf(mxn * g);
    float on  = fminf(tt, MAXN);
    *coef = on / mxn;
    *onorm = on;
}

// u <- proj(mob_add(u, v)); u2 = |u|^2, v2 = |v|^2. Returns post-proj norm.
__device__ __forceinline__ float mob_add_frag(float* u, const float* v,
                                              float u2, float v2, float* sbuf) {
    float duv = 0.f;
    #pragma unroll
    for (int i = 0; i < LPT; ++i) duv += u[i] * v[i];
    duv = block_sum(duv, sbuf);
    float cu  = 1.f + 2.f * duv + v2;
    float cv  = 1.f - u2;
    float den = fmaxf(1.f + 2.f * duv + u2 * v2, MINN);
    float s2 = 0.f;
    #pragma unroll
    for (int i = 0; i < LPT; ++i) {
        float nm = cu * u[i] + cv * v[i];
        u[i] = nm;
        s2 += nm * nm;
    }
    s2 = block_sum(s2, sbuf);
    float n  = sqrtf(fmaxf(s2 / (den * den), MINN));
    float sc = ((n > MAXN) ? MAXN / n : 1.f) / den;
    #pragma unroll
    for (int i = 0; i < LPT; ++i) u[i] *= sc;
    return fminf(n, MAXN);
}

// ---------- K0: weight f32 [K,N] -> bf16 transposed [N,K] ----------

struct TransBatch { const float* W[5]; u16* Wt[5]; };

__global__ __launch_bounds__(256) void wtrans(TransBatch tb) {
    const float* W = tb.W[blockIdx.z];
    u16* Wt = tb.Wt[blockIdx.z];
    __shared__ float tile[32][33];
    int n0 = blockIdx.x * 32, k0 = blockIdx.y * 32;
    int tc = threadIdx.x & 31, tr = threadIdx.x >> 5;   // tr in 0..7
    #pragma unroll
    for (int i = 0; i < 4; ++i) {
        int r = tr + i * 8;
        tile[r][tc] = W[(size_t)(k0 + r) * D + n0 + tc];
    }
    __syncthreads();
    #pragma unroll
    for (int i = 0; i < 4; ++i) {
        int r = tr + i * 8;
        Wt[(size_t)(n0 + r) * D + k0 + tc] = f2bf(tile[tc][r]);
    }
}

// ---------- K1: project inputs, emit bf16 copies + g scalars ----------

__global__ __launch_bounds__(256) void prep(
    const float* __restrict__ hx, const float* __restrict__ h,
    u16* __restrict__ hx_bf, u16* __restrict__ h_bf,
    float* __restrict__ h_proj, float* __restrict__ g_x, float* __restrict__ g_h) {
    __shared__ float sbuf[4];
    int b = blockIdx.x, t = threadIdx.x;
    size_t off = (size_t)b * D;

    // hyp_x row
    {
        float xv[LPT]; float s = 0.f;
        #pragma unroll
        for (int i = 0; i < LPT; ++i) { xv[i] = hx[off + t + 256 * i]; s += xv[i] * xv[i]; }
        float n = sqrtf(fmaxf(block_sum(s, sbuf), MINN));
        float scale = (n > MAXN) ? MAXN / n : 1.0f;
        float xn = fminf(n, MAXN);
        #pragma unroll
        for (int i = 0; i < LPT; ++i) hx_bf[off + t + 256 * i] = f2bf(xv[i] * scale);
        if (t == 0) g_x[b] = artanh_(xn) / xn;
    }
    // hidden row
    {
        float xv[LPT]; float s = 0.f;
        #pragma unroll
        for (int i = 0; i < LPT; ++i) { xv[i] = h[off + t + 256 * i]; s += xv[i] * xv[i]; }
        float n = sqrtf(fmaxf(block_sum(s, sbuf), MINN));
        float scale = (n > MAXN) ? MAXN / n : 1.0f;
        float xn = fminf(n, MAXN);
        #pragma unroll
        for (int i = 0; i < LPT; ++i) {
            float pv = xv[i] * scale;
            h_bf[off + t + 256 * i] = f2bf(pv);
            h_proj[off + t + 256 * i] = pv;
        }
        if (t == 0) g_h[b] = artanh_(xn) / xn;
    }
}

// ---------- GEMM: C[M,N] = A[M,K](bf16) @ Wt[N,K](bf16)^T, fp32 out ----------
// m97-style: global_load_lds width-16 staging, unpadded [128][32] LDS tiles.

struct GemmBatch { const u16* A[4]; const u16* W[4]; float* C[4]; int koff[4]; int klen[4]; };

__global__ __launch_bounds__(256) void gemm_bt(GemmBatch gb) {
    int z = blockIdx.z;
    const u16* __restrict__ A = gb.A[z];
    const u16* __restrict__ W = gb.W[z];
    float* __restrict__ C = gb.C[z];
    int koff = gb.koff[z], klen = gb.klen[z];

    __shared__ u16 As[128 * 32];   // 8 KB, no pad (global_load_lds constraint)
    __shared__ u16 Ws[128 * 32];

    int t = threadIdx.x;
    int wave = t >> 6, lane = t & 63;
    int wr = wave >> 1, wc = wave & 1;       // 2x2 wave grid, each 64x64
    int quad = lane >> 4, l16 = lane & 15;
    int brow = blockIdx.y * 128, bcol = blockIdx.x * 128;

    // staging addresses: wave `wave` loads rows [32*wave, 32*wave+32) of both tiles
    int ra = 32 * wave + (lane >> 2);
    int sa = (lane & 3) * 8;
    const u16* pa0 = A + (size_t)(brow + ra) * D + koff + sa;
    const u16* pa1 = pa0 + (size_t)16 * D;
    const u16* pw0 = W + (size_t)(bcol + ra) * D + koff + sa;
    const u16* pw1 = pw0 + (size_t)16 * D;
    u16* la0 = &As[(32 * wave) * 32];        // wave-uniform LDS bases
    u16* la1 = &As[(32 * wave + 16) * 32];
    u16* lw0 = &Ws[(32 * wave) * 32];
    u16* lw1 = &Ws[(32 * wave + 16) * 32];

    floatx4 acc[4][4];
    #pragma unroll
    for (int i = 0; i < 4; ++i)
        #pragma unroll
        for (int j = 0; j < 4; ++j)
            #pragma unroll
            for (int e = 0; e < 4; ++e) acc[i][j][e] = 0.f;

    for (int k0 = 0; k0 < klen; k0 += 32) {
        __syncthreads();                     // everyone done reading prev tile
        gl_lds16(pa0 + k0, la0);
        gl_lds16(pa1 + k0, la1);
        gl_lds16(pw0 + k0, lw0);
        gl_lds16(pw1 + k0, lw1);
        __syncthreads();                     // vmcnt drained before barrier

        bf16x8 af[4], bfv[4];
        #pragma unroll
        for (int i = 0; i < 4; ++i)
            af[i] = *(const bf16x8*)(&As[(wr * 64 + i * 16 + l16) * 32 + quad * 8]);
        #pragma unroll
        for (int j = 0; j < 4; ++j)
            bfv[j] = *(const bf16x8*)(&Ws[(wc * 64 + j * 16 + l16) * 32 + quad * 8]);
        #pragma unroll
        for (int i = 0; i < 4; ++i)
            #pragma unroll
            for (int j = 0; j < 4; ++j)
                acc[i][j] = __builtin_amdgcn_mfma_f32_16x16x32_bf16(af[i], bfv[j], acc[i][j], 0, 0, 0);
    }

    #pragma unroll
    for (int i = 0; i < 4; ++i) {
        #pragma unroll
        for (int j = 0; j < 4; ++j) {
            int row = brow + wr * 64 + i * 16 + quad * 4;
            int col = bcol + wc * 64 + j * 16 + l16;
            #pragma unroll
            for (int r = 0; r < 4; ++r)
                C[(size_t)(row + r) * D + col] = acc[i][j][r];
        }
    }
}

// ---------- K4: fused middle (finish 4 matvecs, z, r, r_point_h) ----------

__global__ __launch_bounds__(256) void mid_kernel(
    const float* __restrict__ c_wz, const float* __restrict__ c_uz,
    const float* __restrict__ c_wr, const float* __restrict__ c_ur,
    const float* __restrict__ h_proj,
    const float* __restrict__ g_x, const float* __restrict__ g_h,
    const float* __restrict__ b_z, const float* __restrict__ b_r,
    float* __restrict__ z_out, float* __restrict__ uxr_out,
    u16* __restrict__ rph_bf, float* __restrict__ g_rph) {
    __shared__ float sbuf[4];
    int b = blockIdx.x, t = threadIdx.x;
    size_t off = (size_t)b * D;

    float wz[LPT], uz[LPT], wr2[LPT], ur2[LPT], hp[LPT], bz[LPT], br[LPT], zz[LPT];
    float swz = 0, suz = 0, swr = 0, sur = 0;
    #pragma unroll
    for (int i = 0; i < LPT; ++i) {
        int c = t + 256 * i;
        wz[i]  = c_wz[off + c];  swz += wz[i] * wz[i];
        uz[i]  = c_uz[off + c];  suz += uz[i] * uz[i];
        wr2[i] = c_wr[off + c];  swr += wr2[i] * wr2[i];
        ur2[i] = c_ur[off + c];  sur += ur2[i] * ur2[i];
        hp[i]  = h_proj[off + c];
        bz[i]  = b_z[c];
        br[i]  = b_r[c];
    }
    float gh = g_h[b], gx = g_x[b];
    swz = block_sum(swz, sbuf);
    suz = block_sum(suz, sbuf);
    swr = block_sum(swr, sbuf);
    sur = block_sum(sur, sbuf);

    float cwz, nwz, cuz, nuz, cwr, nwr, cur, nur;
    mmm_finish(swz, gh, &cwz, &nwz);
    mmm_finish(suz, gx, &cuz, &nuz);
    mmm_finish(swr, gh, &cwr, &nwr);
    mmm_finish(sur, gx, &cur, &nur);
    #pragma unroll
    for (int i = 0; i < LPT; ++i) {
        wz[i] *= cwz; uz[i] *= cuz; wr2[i] *= cwr; ur2[i] *= cur;
    }

    // |b|^2 reductions
    float sbz = 0, sbr2 = 0;
    #pragma unroll
    for (int i = 0; i < LPT; ++i) { sbz += bz[i] * bz[i]; sbr2 += br[i] * br[i]; }
    sbz  = block_sum(sbz, sbuf);
    sbr2 = block_sum(sbr2, sbuf);

    // z chain
    float n1 = mob_add_frag(wz, uz, nwz * nwz, nuz * nuz, sbuf);
    float n2 = mob_add_frag(wz, bz, n1 * n1, sbz, sbuf);
    float gz = artanh_(n2) / n2;
    #pragma unroll
    for (int i = 0; i < LPT; ++i) {
        zz[i] = sigmoid_(gz * wz[i]);
        z_out[off + t + 256 * i] = zz[i];
    }

    // r chain
    float n1r = mob_add_frag(wr2, ur2, nwr * nwr, nur * nur, sbuf);
    float n2r = mob_add_frag(wr2, br, n1r * n1r, sbr2, sbuf);
    float gr = artanh_(n2r) / n2r;
    #pragma unroll
    for (int i = 0; i < LPT; ++i) br[i] = sigmoid_(gr * wr2[i]);   // br := r

    // r_point_h = exp_map_zero(log_map_zero(h_proj) * r)
    float sv = 0.f;
    #pragma unroll
    for (int i = 0; i < LPT; ++i) {
        float v = gh * hp[i] * br[i];
        wz[i] = v;                 // reuse wz as v
        sv += v * v;
    }
    sv = block_sum(sv, sbuf);
    float nv = sqrtf(fmaxf(sv, MINN));
    float th = fminf(tanhf(nv), MAXN);
    float cr = th / nv;
    #pragma unroll
    for (int i = 0; i < LPT; ++i) {
        rph_bf[off + t + 256 * i] = f2bf(wz[i] * cr);
        uxr_out[off + t + 256 * i] = ur2[i];   // finished UxR (reused for h_tilde)
    }
    if (t == 0) g_rph[b] = artanh_(th) / th;
}

// ---------- K6: epilogue ----------

__global__ __launch_bounds__(256) void fin_kernel(
    const float* __restrict__ c_wh_a, const float* __restrict__ c_wh_b,
    const float* __restrict__ uxr,
    const float* __restrict__ z_in, const float* __restrict__ h_proj,
    const float* __restrict__ g_rph, const float* __restrict__ b_h,
    float* __restrict__ out) {
    __shared__ float sbuf[4];
    int b = blockIdx.x, t = threadIdx.x;
    size_t off = (size_t)b * D;

    float wh[LPT], ux[LPT], zz[LPT], hp[LPT], bh[LPT];
    float swh = 0, sux = 0, shp = 0, sbh = 0;
    #pragma unroll
    for (int i = 0; i < LPT; ++i) {
        int c = t + 256 * i;
        wh[i] = c_wh_a[off + c] + c_wh_b[off + c];   // K-split partials
        swh += wh[i] * wh[i];
        ux[i] = uxr[off + c];   sux += ux[i] * ux[i];
        zz[i] = z_in[off + c];
        hp[i] = h_proj[off + c]; shp += hp[i] * hp[i];
        bh[i] = b_h[c];         sbh += bh[i] * bh[i];
    }
    swh = block_sum(swh, sbuf);
    sux = block_sum(sux, sbuf);
    shp = block_sum(shp, sbuf);
    sbh = block_sum(sbh, sbuf);

    float cwh, nwh;
    mmm_finish(swh, g_rph[b], &cwh, &nwh);
    #pragma unroll
    for (int i = 0; i < LPT; ++i) wh[i] *= cwh;

    // h_tilde = mob_add(mob_add(WhH, UxR), b_h)
    float n1  = mob_add_frag(wh, ux, nwh * nwh, sux, sbuf);
    float nht = mob_add_frag(wh, bh, n1 * n1, sbh, sbuf);

    // minus = mob_add(-h_proj, h_tilde)
    #pragma unroll
    for (int i = 0; i < LPT; ++i) ux[i] = -hp[i];   // reuse ux
    float nm = mob_add_frag(ux, wh, shp, nht * nht, sbuf);

    // emz = exp_map_zero(log_map_zero(minus) * z)
    float lm = artanh_(nm) / nm;
    float sv = 0.f;
    #pragma unroll
    for (int i = 0; i < LPT; ++i) {
        float v = lm * ux[i] * zz[i];
        ux[i] = v;
        sv += v * v;
    }
    sv = block_sum(sv, sbuf);
    float nv = sqrtf(fmaxf(sv, MINN));
    float th = fminf(tanhf(nv), MAXN);
    float ce = th / nv;
    #pragma unroll
    for (int i = 0; i < LPT; ++i) ux[i] *= ce;

    // new_h = mob_add(h_proj, emz)
    mob_add_frag(hp, ux, shp, th * th, sbuf);
    #pragma unroll
    for (int i = 0; i < LPT; ++i) out[off + t + 256 * i] = hp[i];
}

// ---------- launch ----------

extern "C" void kernel_launch(void* const* d_in, const int* in_sizes, int n_in,
                              void* d_out, int out_size, void* d_ws, size_t ws_size,
                              hipStream_t stream) {
    const float* hyp_x  = (const float*)d_in[0];
    const float* hidden = (const float*)d_in[1];
    const float* w_z = (const float*)d_in[2];
    const float* w_r = (const float*)d_in[3];
    const float* w_h = (const float*)d_in[4];
    const float* u_z = (const float*)d_in[5];
    const float* u_r = (const float*)d_in[6];
    const float* b_z = (const float*)d_in[7];
    const float* b_r = (const float*)d_in[8];
    const float* b_h = (const float*)d_in[9];
    float* out = (float*)d_out;

    int B = in_sizes[1] / D;   // 2048

    char* ws = (char*)d_ws;
    size_t o = 0;
    auto alloc = [&](size_t bytes) -> void* {
        void* p = ws + o;
        o += (bytes + 255) & ~(size_t)255;
        return p;
    };
    u16* wt[5];
    for (int i = 0; i < 5; ++i) wt[i] = (u16*)alloc((size_t)D * D * 2);
    u16* hx_bf   = (u16*)alloc((size_t)B * D * 2);
    u16* h_bf    = (u16*)alloc((size_t)B * D * 2);
    float* h_proj = (float*)alloc((size_t)B * D * 4);
    float* g_x   = (float*)alloc((size_t)B * 4);
    float* g_h   = (float*)alloc((size_t)B * 4);
    float* g_rph = (float*)alloc((size_t)B * 4);
    float* c0 = (float*)alloc((size_t)B * D * 4);
    float* c1 = (float*)alloc((size_t)B * D * 4);
    float* c2 = (float*)alloc((size_t)B * D * 4);
    float* c3 = (float*)alloc((size_t)B * D * 4);
    float* z_buf = (float*)alloc((size_t)B * D * 4);
    float* uxr   = (float*)alloc((size_t)B * D * 4);
    u16* rph     = (u16*)alloc((size_t)B * D * 2);

    // K0: transpose+convert 5 weight matrices (order: w_z,w_r,w_h,u_z,u_r)
    TransBatch tb;
    tb.W[0] = w_z; tb.W[1] = w_r; tb.W[2] = w_h; tb.W[3] = u_z; tb.W[4] = u_r;
    for (int i = 0; i < 5; ++i) tb.Wt[i] = wt[i];
    wtrans<<<dim3(D / 32, D / 32, 5), 256, 0, stream>>>(tb);

    // K1: projections
    prep<<<dim3(B), 256, 0, stream>>>(hyp_x, hidden, hx_bf, h_bf, h_proj, g_x, g_h);

    // G1: c0 = h@w_z, c1 = x@u_z, c2 = h@w_r, c3 = x@u_r
    GemmBatch g1;
    g1.A[0] = h_bf;  g1.W[0] = wt[0]; g1.C[0] = c0;
    g1.A[1] = hx_bf; g1.W[1] = wt[3]; g1.C[1] = c1;
    g1.A[2] = h_bf;  g1.W[2] = wt[1]; g1.C[2] = c2;
    g1.A[3] = hx_bf; g1.W[3] = wt[4]; g1.C[3] = c3;
    for (int i = 0; i < 4; ++i) { g1.koff[i] = 0; g1.klen[i] = D; }
    gemm_bt<<<dim3(D / 128, B / 128, 4), 256, 0, stream>>>(g1);

    // K4: middle fusion
    mid_kernel<<<dim3(B), 256, 0, stream>>>(c0, c1, c2, c3, h_proj, g_x, g_h,
                                            b_z, b_r, z_buf, uxr, rph, g_rph);

    // G2: K-split r_point_h @ w_h into c2 (K 0..1024) + c3 (K 1024..2048)
    GemmBatch g2;
    g2.A[0] = rph; g2.W[0] = wt[2]; g2.C[0] = c2; g2.koff[0] = 0;    g2.klen[0] = D / 2;
    g2.A[1] = rph; g2.W[1] = wt[2]; g2.C[1] = c3; g2.koff[1] = D/2;  g2.klen[1] = D / 2;
    g2.A[2] = g2.A[0]; g2.W[2] = g2.W[0]; g2.C[2] = g2.C[0]; g2.koff[2] = 0; g2.klen[2] = 0;
    g2.A[3] = g2.A[0]; g2.W[3] = g2.W[0]; g2.C[3] = g2.C[0]; g2.koff[3] = 0; g2.klen[3] = 0;
    gemm_bt<<<dim3(D / 128, B / 128, 2), 256, 0, stream>>>(g2);

    // K6: epilogue (sums the two K-partials of Wh @ r_point_h)
    fin_kernel<<<dim3(B), 256, 0, stream>>>(c2, c3, uxr, z_buf, h_proj, g_rph, b_h, out);
}

// Round 3
// 338.045 us; speedup vs baseline: 1.8470x; 1.0337x over previous
//
#include <hip/hip_runtime.h>
#include <hip/hip_bf16.h>
#include <math.h>

#define EPS 1e-5f
#define MAXN (1.0f - EPS)
#define MINN 1e-10f

constexpr int D = 2048;      // Dh == Din == 2048 for this problem
constexpr int LPT = 8;       // elements per thread in row kernels (D / 256)

typedef unsigned short u16;
typedef __bf16 bf16x8 __attribute__((ext_vector_type(8)));
typedef float floatx4 __attribute__((ext_vector_type(4)));

// ---------- small helpers ----------

__device__ __forceinline__ u16 f2bf(float f) {
    union { float f; unsigned u; } v; v.f = f;
    unsigned r = v.u + 0x7FFFu + ((v.u >> 16) & 1u);   // RNE
    return (u16)(r >> 16);
}

__device__ __forceinline__ float artanh_(float x) {
    x = fminf(fmaxf(x, -1.0f + EPS), 1.0f - EPS);
    return 0.5f * logf((1.0f + x) / (1.0f - x));
}

__device__ __forceinline__ float sigmoid_(float x) {
    return 1.0f / (1.0f + expf(-x));
}

// async global->LDS, 16 bytes/lane; lds base must be wave-uniform
__device__ __forceinline__ void gl_lds16(const u16* g, u16* l) {
    __builtin_amdgcn_global_load_lds(
        (const __attribute__((address_space(1))) unsigned int*)g,
        (__attribute__((address_space(3))) unsigned int*)l, 16, 0, 0);
}

// all 256 threads must call; 4 waves assumed
__device__ __forceinline__ float block_sum(float v, float* sbuf) {
    #pragma unroll
    for (int off = 32; off >= 1; off >>= 1) v += __shfl_xor(v, off, 64);
    int w = threadIdx.x >> 6;
    __syncthreads();                       // protect sbuf from previous call
    if ((threadIdx.x & 63) == 0) sbuf[w] = v;
    __syncthreads();
    return sbuf[0] + sbuf[1] + sbuf[2] + sbuf[3];
}

// finish mob_mat_mul: given |Mx|^2 and g = artanh(x_n)/x_n, return scale coef
// (out = coef * Mx_raw) and the output norm (post-proj).
__device__ __forceinline__ void mmm_finish(float sum2, float g, float* coef, float* onorm) {
    float mxn = sqrtf(fmaxf(sum2, MINN));
    float tt  = tanhf(mxn * g);
    float on  = fminf(tt, MAXN);
    *coef = on / mxn;
    *onorm = on;
}

// u <- proj(mob_add(u, v)); u2 = |u|^2, v2 = |v|^2. Returns post-proj norm.
__device__ __forceinline__ float mob_add_frag(float* u, const float* v,
                                              float u2, float v2, float* sbuf) {
    float duv = 0.f;
    #pragma unroll
    for (int i = 0; i < LPT; ++i) duv += u[i] * v[i];
    duv = block_sum(duv, sbuf);
    float cu  = 1.f + 2.f * duv + v2;
    float cv  = 1.f - u2;
    float den = fmaxf(1.f + 2.f * duv + u2 * v2, MINN);
    float s2 = 0.f;
    #pragma unroll
    for (int i = 0; i < LPT; ++i) {
        float nm = cu * u[i] + cv * v[i];
        u[i] = nm;
        s2 += nm * nm;
    }
    s2 = block_sum(s2, sbuf);
    float n  = sqrtf(fmaxf(s2 / (den * den), MINN));
    float sc = ((n > MAXN) ? MAXN / n : 1.f) / den;
    #pragma unroll
    for (int i = 0; i < LPT; ++i) u[i] *= sc;
    return fminf(n, MAXN);
}

// ---------- K0: weight f32 [K,N] -> bf16 transposed [N,K] ----------
// 64x64 tiles; float4 coalesced reads, bf16x8 (16B) coalesced writes.

struct TransBatch { const float* W[5]; u16* Wt[5]; };

__global__ __launch_bounds__(256) void wtrans(TransBatch tb) {
    const float* W = tb.W[blockIdx.z];
    u16* Wt = tb.Wt[blockIdx.z];
    __shared__ float tile[64 * 65];        // stride 65: conflict-free both phases
    int n0 = blockIdx.x * 64, k0 = blockIdx.y * 64;
    int t = threadIdx.x;

    // load: 4 passes, each 16 rows x 64 cols (float4 per thread)
    int lr = t >> 4, lc = (t & 15) * 4;
    #pragma unroll
    for (int p = 0; p < 4; ++p) {
        int r = lr + p * 16;
        float4 v = *(const float4*)(W + (size_t)(k0 + r) * D + n0 + lc);
        tile[r * 65 + lc + 0] = v.x;
        tile[r * 65 + lc + 1] = v.y;
        tile[r * 65 + lc + 2] = v.z;
        tile[r * 65 + lc + 3] = v.w;
    }
    __syncthreads();

    // store: 2 passes, each 32 n-rows; thread writes 8 bf16 (16B) along k
    int wn = t >> 3, ws = (t & 7) * 8;
    #pragma unroll
    for (int p = 0; p < 2; ++p) {
        int n = wn + p * 32;
        u16 pk[8];
        #pragma unroll
        for (int j = 0; j < 8; ++j) pk[j] = f2bf(tile[(ws + j) * 65 + n]);
        *(uint4*)(Wt + (size_t)(n0 + n) * D + k0 + ws) = *(uint4*)pk;
    }
}

// ---------- K1: project inputs, emit bf16 copies + g scalars ----------

__global__ __launch_bounds__(256) void prep(
    const float* __restrict__ hx, const float* __restrict__ h,
    u16* __restrict__ hx_bf, u16* __restrict__ h_bf,
    float* __restrict__ h_proj, float* __restrict__ g_x, float* __restrict__ g_h) {
    __shared__ float sbuf[4];
    int b = blockIdx.x, t = threadIdx.x;
    size_t off = (size_t)b * D;

    // hyp_x row
    {
        float xv[LPT]; float s = 0.f;
        #pragma unroll
        for (int i = 0; i < LPT; ++i) { xv[i] = hx[off + t + 256 * i]; s += xv[i] * xv[i]; }
        float n = sqrtf(fmaxf(block_sum(s, sbuf), MINN));
        float scale = (n > MAXN) ? MAXN / n : 1.0f;
        float xn = fminf(n, MAXN);
        #pragma unroll
        for (int i = 0; i < LPT; ++i) hx_bf[off + t + 256 * i] = f2bf(xv[i] * scale);
        if (t == 0) g_x[b] = artanh_(xn) / xn;
    }
    // hidden row
    {
        float xv[LPT]; float s = 0.f;
        #pragma unroll
        for (int i = 0; i < LPT; ++i) { xv[i] = h[off + t + 256 * i]; s += xv[i] * xv[i]; }
        float n = sqrtf(fmaxf(block_sum(s, sbuf), MINN));
        float scale = (n > MAXN) ? MAXN / n : 1.0f;
        float xn = fminf(n, MAXN);
        #pragma unroll
        for (int i = 0; i < LPT; ++i) {
            float pv = xv[i] * scale;
            h_bf[off + t + 256 * i] = f2bf(pv);
            h_proj[off + t + 256 * i] = pv;
        }
        if (t == 0) g_h[b] = artanh_(xn) / xn;
    }
}

// ---------- GEMM: C[M,N] = A[M,K](bf16) @ Wt[N,K](bf16)^T, fp32 out ----------
// BK=64, global_load_lds width-16 staging with XOR-swizzled segment order so
// the ds_read_b128 fragment reads hit all 32 banks (2 lanes/bank = free).
// LDS layout: tile[row][64] u16, physical seg p holds global seg p ^ (row&7).

struct GemmBatch { const u16* A[4]; const u16* W[4]; float* C[4]; int koff[4]; };

template<int KLEN>
__global__ __launch_bounds__(256) void gemm_bt(GemmBatch gb) {
    int z = blockIdx.z;
    const u16* __restrict__ A = gb.A[z];
    const u16* __restrict__ W = gb.W[z];
    float* __restrict__ C = gb.C[z];
    int koff = gb.koff[z];

    __shared__ u16 As[128 * 64];   // 16 KB
    __shared__ u16 Ws[128 * 64];   // 16 KB

    int t = threadIdx.x;
    int wave = t >> 6, lane = t & 63;
    int wr = wave >> 1, wc = wave & 1;       // 2x2 wave grid, each 64x64
    int quad = lane >> 4, l16 = lane & 15;
    int brow = blockIdx.y * 128, bcol = blockIdx.x * 128;

    // staging: wave handles rows [32*wave, 32*wave+32), 4 issues of 8 rows.
    // lane l -> row = 32w + 8i + (l>>3), fetches global seg (l&7)^((l>>3)&7).
    int srow = 32 * wave + (lane >> 3);
    int sseg = (lane & 7) ^ ((lane >> 3) & 7);
    const u16* pa = A + (size_t)(brow + srow) * D + koff + sseg * 8;
    const u16* pw = W + (size_t)(bcol + srow) * D + koff + sseg * 8;
    u16* lbA = &As[wave * 2048];             // wave-uniform LDS bases
    u16* lbW = &Ws[wave * 2048];

    floatx4 acc[4][4];
    #pragma unroll
    for (int i = 0; i < 4; ++i)
        #pragma unroll
        for (int j = 0; j < 4; ++j)
            #pragma unroll
            for (int e = 0; e < 4; ++e) acc[i][j][e] = 0.f;

    int xsw = l16 & 7;                       // fragment-read swizzle term

    for (int k0 = 0; k0 < KLEN; k0 += 64) {
        __syncthreads();                     // everyone done reading prev tile
        #pragma unroll
        for (int i = 0; i < 4; ++i) {
            gl_lds16(pa + (size_t)(8 * i) * D + k0, lbA + i * 512);
            gl_lds16(pw + (size_t)(8 * i) * D + k0, lbW + i * 512);
        }
        __syncthreads();                     // vmcnt drained before barrier

        #pragma unroll
        for (int kk = 0; kk < 2; ++kk) {
            bf16x8 af[4], bfv[4];
            int ps = ((kk * 4 + quad) ^ xsw) * 8;
            #pragma unroll
            for (int i = 0; i < 4; ++i)
                af[i] = *(const bf16x8*)(&As[(wr * 64 + i * 16 + l16) * 64 + ps]);
            #pragma unroll
            for (int j = 0; j < 4; ++j)
                bfv[j] = *(const bf16x8*)(&Ws[(wc * 64 + j * 16 + l16) * 64 + ps]);
            #pragma unroll
            for (int i = 0; i < 4; ++i)
                #pragma unroll
                for (int j = 0; j < 4; ++j)
                    acc[i][j] = __builtin_amdgcn_mfma_f32_16x16x32_bf16(af[i], bfv[j], acc[i][j], 0, 0, 0);
        }
    }

    #pragma unroll
    for (int i = 0; i < 4; ++i) {
        #pragma unroll
        for (int j = 0; j < 4; ++j) {
            int row = brow + wr * 64 + i * 16 + quad * 4;
            int col = bcol + wc * 64 + j * 16 + l16;
            #pragma unroll
            for (int r = 0; r < 4; ++r)
                C[(size_t)(row + r) * D + col] = acc[i][j][r];
        }
    }
}

// ---------- K4: fused middle (finish 4 matvecs, z, r, r_point_h) ----------

__global__ __launch_bounds__(256) void mid_kernel(
    const float* __restrict__ c_wz, const float* __restrict__ c_uz,
    const float* __restrict__ c_wr, const float* __restrict__ c_ur,
    const float* __restrict__ h_proj,
    const float* __restrict__ g_x, const float* __restrict__ g_h,
    const float* __restrict__ b_z, const float* __restrict__ b_r,
    float* __restrict__ z_out, float* __restrict__ uxr_out,
    u16* __restrict__ rph_bf, float* __restrict__ g_rph) {
    __shared__ float sbuf[4];
    int b = blockIdx.x, t = threadIdx.x;
    size_t off = (size_t)b * D;

    float wz[LPT], uz[LPT], wr2[LPT], ur2[LPT], hp[LPT], bz[LPT], br[LPT], zz[LPT];
    float swz = 0, suz = 0, swr = 0, sur = 0;
    #pragma unroll
    for (int i = 0; i < LPT; ++i) {
        int c = t + 256 * i;
        wz[i]  = c_wz[off + c];  swz += wz[i] * wz[i];
        uz[i]  = c_uz[off + c];  suz += uz[i] * uz[i];
        wr2[i] = c_wr[off + c];  swr += wr2[i] * wr2[i];
        ur2[i] = c_ur[off + c];  sur += ur2[i] * ur2[i];
        hp[i]  = h_proj[off + c];
        bz[i]  = b_z[c];
        br[i]  = b_r[c];
    }
    float gh = g_h[b], gx = g_x[b];
    swz = block_sum(swz, sbuf);
    suz = block_sum(suz, sbuf);
    swr = block_sum(swr, sbuf);
    sur = block_sum(sur, sbuf);

    float cwz, nwz, cuz, nuz, cwr, nwr, cur, nur;
    mmm_finish(swz, gh, &cwz, &nwz);
    mmm_finish(suz, gx, &cuz, &nuz);
    mmm_finish(swr, gh, &cwr, &nwr);
    mmm_finish(sur, gx, &cur, &nur);
    #pragma unroll
    for (int i = 0; i < LPT; ++i) {
        wz[i] *= cwz; uz[i] *= cuz; wr2[i] *= cwr; ur2[i] *= cur;
    }

    // |b|^2 reductions
    float sbz = 0, sbr2 = 0;
    #pragma unroll
    for (int i = 0; i < LPT; ++i) { sbz += bz[i] * bz[i]; sbr2 += br[i] * br[i]; }
    sbz  = block_sum(sbz, sbuf);
    sbr2 = block_sum(sbr2, sbuf);

    // z chain
    float n1 = mob_add_frag(wz, uz, nwz * nwz, nuz * nuz, sbuf);
    float n2 = mob_add_frag(wz, bz, n1 * n1, sbz, sbuf);
    float gz = artanh_(n2) / n2;
    #pragma unroll
    for (int i = 0; i < LPT; ++i) {
        zz[i] = sigmoid_(gz * wz[i]);
        z_out[off + t + 256 * i] = zz[i];
    }

    // r chain
    float n1r = mob_add_frag(wr2, ur2, nwr * nwr, nur * nur, sbuf);
    float n2r = mob_add_frag(wr2, br, n1r * n1r, sbr2, sbuf);
    float gr = artanh_(n2r) / n2r;
    #pragma unroll
    for (int i = 0; i < LPT; ++i) br[i] = sigmoid_(gr * wr2[i]);   // br := r

    // r_point_h = exp_map_zero(log_map_zero(h_proj) * r)
    float sv = 0.f;
    #pragma unroll
    for (int i = 0; i < LPT; ++i) {
        float v = gh * hp[i] * br[i];
        wz[i] = v;                 // reuse wz as v
        sv += v * v;
    }
    sv = block_sum(sv, sbuf);
    float nv = sqrtf(fmaxf(sv, MINN));
    float th = fminf(tanhf(nv), MAXN);
    float cr = th / nv;
    #pragma unroll
    for (int i = 0; i < LPT; ++i) {
        rph_bf[off + t + 256 * i] = f2bf(wz[i] * cr);
        uxr_out[off + t + 256 * i] = ur2[i];   // finished UxR (reused for h_tilde)
    }
    if (t == 0) g_rph[b] = artanh_(th) / th;
}

// ---------- K6: epilogue ----------

__global__ __launch_bounds__(256) void fin_kernel(
    const float* __restrict__ p0, const float* __restrict__ p1,
    const float* __restrict__ p2, const float* __restrict__ p3,
    const float* __restrict__ uxr,
    const float* __restrict__ z_in, const float* __restrict__ h_proj,
    const float* __restrict__ g_rph, const float* __restrict__ b_h,
    float* __restrict__ out) {
    __shared__ float sbuf[4];
    int b = blockIdx.x, t = threadIdx.x;
    size_t off = (size_t)b * D;

    float wh[LPT], ux[LPT], zz[LPT], hp[LPT], bh[LPT];
    float swh = 0, sux = 0, shp = 0, sbh = 0;
    #pragma unroll
    for (int i = 0; i < LPT; ++i) {
        int c = t + 256 * i;
        wh[i] = p0[off + c] + p1[off + c] + p2[off + c] + p3[off + c];  // K-split partials
        swh += wh[i] * wh[i];
        ux[i] = uxr[off + c];   sux += ux[i] * ux[i];
        zz[i] = z_in[off + c];
        hp[i] = h_proj[off + c]; shp += hp[i] * hp[i];
        bh[i] = b_h[c];         sbh += bh[i] * bh[i];
    }
    swh = block_sum(swh, sbuf);
    sux = block_sum(sux, sbuf);
    shp = block_sum(shp, sbuf);
    sbh = block_sum(sbh, sbuf);

    float cwh, nwh;
    mmm_finish(swh, g_rph[b], &cwh, &nwh);
    #pragma unroll
    for (int i = 0; i < LPT; ++i) wh[i] *= cwh;

    // h_tilde = mob_add(mob_add(WhH, UxR), b_h)
    float n1  = mob_add_frag(wh, ux, nwh * nwh, sux, sbuf);
    float nht = mob_add_frag(wh, bh, n1 * n1, sbh, sbuf);

    // minus = mob_add(-h_proj, h_tilde)
    #pragma unroll
    for (int i = 0; i < LPT; ++i) ux[i] = -hp[i];   // reuse ux
    float nm = mob_add_frag(ux, wh, shp, nht * nht, sbuf);

    // emz = exp_map_zero(log_map_zero(minus) * z)
    float lm = artanh_(nm) / nm;
    float sv = 0.f;
    #pragma unroll
    for (int i = 0; i < LPT; ++i) {
        float v = lm * ux[i] * zz[i];
        ux[i] = v;
        sv += v * v;
    }
    sv = block_sum(sv, sbuf);
    float nv = sqrtf(fmaxf(sv, MINN));
    float th = fminf(tanhf(nv), MAXN);
    float ce = th / nv;
    #pragma unroll
    for (int i = 0; i < LPT; ++i) ux[i] *= ce;

    // new_h = mob_add(h_proj, emz)
    mob_add_frag(hp, ux, shp, th * th, sbuf);
    #pragma unroll
    for (int i = 0; i < LPT; ++i) out[off + t + 256 * i] = hp[i];
}

// ---------- launch ----------

extern "C" void kernel_launch(void* const* d_in, const int* in_sizes, int n_in,
                              void* d_out, int out_size, void* d_ws, size_t ws_size,
                              hipStream_t stream) {
    const float* hyp_x  = (const float*)d_in[0];
    const float* hidden = (const float*)d_in[1];
    const float* w_z = (const float*)d_in[2];
    const float* w_r = (const float*)d_in[3];
    const float* w_h = (const float*)d_in[4];
    const float* u_z = (const float*)d_in[5];
    const float* u_r = (const float*)d_in[6];
    const float* b_z = (const float*)d_in[7];
    const float* b_r = (const float*)d_in[8];
    const float* b_h = (const float*)d_in[9];
    float* out = (float*)d_out;

    int B = in_sizes[1] / D;   // 2048

    char* ws = (char*)d_ws;
    size_t o = 0;
    auto alloc = [&](size_t bytes) -> void* {
        void* p = ws + o;
        o += (bytes + 255) & ~(size_t)255;
        return p;
    };
    u16* wt[5];
    for (int i = 0; i < 5; ++i) wt[i] = (u16*)alloc((size_t)D * D * 2);
    u16* hx_bf   = (u16*)alloc((size_t)B * D * 2);
    u16* h_bf    = (u16*)alloc((size_t)B * D * 2);
    float* h_proj = (float*)alloc((size_t)B * D * 4);
    float* g_x   = (float*)alloc((size_t)B * 4);
    float* g_h   = (float*)alloc((size_t)B * 4);
    float* g_rph = (float*)alloc((size_t)B * 4);
    float* c0 = (float*)alloc((size_t)B * D * 4);
    float* c1 = (float*)alloc((size_t)B * D * 4);
    float* c2 = (float*)alloc((size_t)B * D * 4);
    float* c3 = (float*)alloc((size_t)B * D * 4);
    float* z_buf = (float*)alloc((size_t)B * D * 4);
    float* uxr   = (float*)alloc((size_t)B * D * 4);
    u16* rph     = (u16*)alloc((size_t)B * D * 2);

    // K0: transpose+convert 5 weight matrices (order: w_z,w_r,w_h,u_z,u_r)
    TransBatch tb;
    tb.W[0] = w_z; tb.W[1] = w_r; tb.W[2] = w_h; tb.W[3] = u_z; tb.W[4] = u_r;
    for (int i = 0; i < 5; ++i) tb.Wt[i] = wt[i];
    wtrans<<<dim3(D / 64, D / 64, 5), 256, 0, stream>>>(tb);

    // K1: projections
    prep<<<dim3(B), 256, 0, stream>>>(hyp_x, hidden, hx_bf, h_bf, h_proj, g_x, g_h);

    // G1: c0 = h@w_z, c1 = x@u_z, c2 = h@w_r, c3 = x@u_r
    GemmBatch g1;
    g1.A[0] = h_bf;  g1.W[0] = wt[0]; g1.C[0] = c0;
    g1.A[1] = hx_bf; g1.W[1] = wt[3]; g1.C[1] = c1;
    g1.A[2] = h_bf;  g1.W[2] = wt[1]; g1.C[2] = c2;
    g1.A[3] = hx_bf; g1.W[3] = wt[4]; g1.C[3] = c3;
    for (int i = 0; i < 4; ++i) g1.koff[i] = 0;
    gemm_bt<2048><<<dim3(D / 128, B / 128, 4), 256, 0, stream>>>(g1);

    // K4: middle fusion
    mid_kernel<<<dim3(B), 256, 0, stream>>>(c0, c1, c2, c3, h_proj, g_x, g_h,
                                            b_z, b_r, z_buf, uxr, rph, g_rph);

    // G2: 4-way K-split r_point_h @ w_h -> partials in c0..c3
    GemmBatch g2;
    float* cb[4] = {c0, c1, c2, c3};
    for (int s = 0; s < 4; ++s) {
        g2.A[s] = rph; g2.W[s] = wt[2]; g2.C[s] = cb[s]; g2.koff[s] = s * 512;
    }
    gemm_bt<512><<<dim3(D / 128, B / 128, 4), 256, 0, stream>>>(g2);

    // K6: epilogue (sums the four K-partials of Wh @ r_point_h)
    fin_kernel<<<dim3(B), 256, 0, stream>>>(c0, c1, c2, c3, uxr, z_buf, h_proj,
                                            g_rph, b_h, out);
}

// Round 4
// 324.736 us; speedup vs baseline: 1.9227x; 1.0410x over previous
//
#include <hip/hip_runtime.h>
#include <hip/hip_bf16.h>
#include <math.h>

#define EPS 1e-5f
#define MAXN (1.0f - EPS)
#define MINN 1e-10f

constexpr int D = 2048;      // Dh == Din == 2048 for this problem

typedef unsigned short u16;
typedef __bf16 bf16x8 __attribute__((ext_vector_type(8)));
typedef float floatx4 __attribute__((ext_vector_type(4)));

// ---------- small helpers ----------

__device__ __forceinline__ u16 f2bf(float f) {
    union { float f; unsigned u; } v; v.f = f;
    unsigned r = v.u + 0x7FFFu + ((v.u >> 16) & 1u);   // RNE
    return (u16)(r >> 16);
}

__device__ __forceinline__ float bf2f(u16 b) {
    union { unsigned u; float f; } v; v.u = ((unsigned)b) << 16; return v.f;
}

// load 8 contiguous bf16 -> float[8] (one 16B load)
__device__ __forceinline__ void load_bf8(const u16* p, float* d) {
    uint4 r = *(const uint4*)p;
    unsigned w[4] = {r.x, r.y, r.z, r.w};
    #pragma unroll
    for (int i = 0; i < 4; ++i) {
        d[2 * i]     = bf2f((u16)(w[i] & 0xFFFFu));
        d[2 * i + 1] = bf2f((u16)(w[i] >> 16));
    }
}

// store float[8] -> 8 contiguous bf16 (one 16B store)
__device__ __forceinline__ void store_bf8(u16* p, const float* s) {
    u16 pk[8];
    #pragma unroll
    for (int i = 0; i < 8; ++i) pk[i] = f2bf(s[i]);
    *(uint4*)p = *(const uint4*)pk;
}

__device__ __forceinline__ void load_f8(const float* p, float* d) {
    *(float4*)(d)     = *(const float4*)(p);
    *(float4*)(d + 4) = *(const float4*)(p + 4);
}

__device__ __forceinline__ void store_f8(float* p, const float* s) {
    *(float4*)(p)     = *(const float4*)(s);
    *(float4*)(p + 4) = *(const float4*)(s + 4);
}

__device__ __forceinline__ float artanh_(float x) {
    x = fminf(fmaxf(x, -1.0f + EPS), 1.0f - EPS);
    return 0.5f * logf((1.0f + x) / (1.0f - x));
}

__device__ __forceinline__ float sigmoid_(float x) {
    return 1.0f / (1.0f + expf(-x));
}

// async global->LDS, 16 bytes/lane; lds base must be wave-uniform
__device__ __forceinline__ void gl_lds16(const u16* g, u16* l) {
    __builtin_amdgcn_global_load_lds(
        (const __attribute__((address_space(1))) unsigned int*)g,
        (__attribute__((address_space(3))) unsigned int*)l, 16, 0, 0);
}

// N simultaneous block-wide sums, ONE barrier pair. 256 threads / 4 waves.
template<int N>
__device__ __forceinline__ void block_sums(float* v, float* sbuf) {
    #pragma unroll
    for (int n = 0; n < N; ++n)
        #pragma unroll
        for (int off = 32; off >= 1; off >>= 1) v[n] += __shfl_xor(v[n], off, 64);
    int w = threadIdx.x >> 6;
    __syncthreads();                       // protect sbuf from previous call
    if ((threadIdx.x & 63) == 0) {
        #pragma unroll
        for (int n = 0; n < N; ++n) sbuf[w * N + n] = v[n];
    }
    __syncthreads();
    #pragma unroll
    for (int n = 0; n < N; ++n)
        v[n] = sbuf[n] + sbuf[N + n] + sbuf[2 * N + n] + sbuf[3 * N + n];
}

// finish mob_mat_mul: given |Mx|^2 and g = artanh(x_n)/x_n, return scale coef
// (out = coef * Mx_raw) and the output norm (post-proj).
__device__ __forceinline__ void mmm_finish(float sum2, float g, float* coef, float* onorm) {
    float mxn = sqrtf(fmaxf(sum2, MINN));
    float tt  = tanhf(mxn * g);
    float on  = fminf(tt, MAXN);
    *coef = on / mxn;
    *onorm = on;
}

// apply mob_add given duv already reduced. |num|^2 computed ANALYTICALLY:
// |cu*u + cv*v|^2 = cu^2 u2 + 2 cu cv duv + cv^2 v2  (no second reduction).
// u <- proj(mob_add(u,v)); returns post-proj norm.
__device__ __forceinline__ float mob_apply(float* u, const float* v,
                                           float u2, float v2, float duv) {
    float cu  = 1.f + 2.f * duv + v2;
    float cv  = 1.f - u2;
    float den = fmaxf(1.f + 2.f * duv + u2 * v2, MINN);
    float s2  = cu * cu * u2 + 2.f * cu * cv * duv + cv * cv * v2;
    float n   = sqrtf(fmaxf(s2 / (den * den), MINN));
    float sc  = ((n > MAXN) ? MAXN / n : 1.f) / den;
    #pragma unroll
    for (int i = 0; i < 8; ++i) u[i] = sc * (cu * u[i] + cv * v[i]);
    return fminf(n, MAXN);
}

// ---------- K0: weight f32 [K,N] -> bf16 transposed [N,K] ----------

struct TransBatch { const float* W[5]; u16* Wt[5]; };

__global__ __launch_bounds__(256) void wtrans(TransBatch tb) {
    const float* W = tb.W[blockIdx.z];
    u16* Wt = tb.Wt[blockIdx.z];
    __shared__ float tile[64 * 65];        // stride 65: conflict-free both phases
    int n0 = blockIdx.x * 64, k0 = blockIdx.y * 64;
    int t = threadIdx.x;

    int lr = t >> 4, lc = (t & 15) * 4;
    #pragma unroll
    for (int p = 0; p < 4; ++p) {
        int r = lr + p * 16;
        float4 v = *(const float4*)(W + (size_t)(k0 + r) * D + n0 + lc);
        tile[r * 65 + lc + 0] = v.x;
        tile[r * 65 + lc + 1] = v.y;
        tile[r * 65 + lc + 2] = v.z;
        tile[r * 65 + lc + 3] = v.w;
    }
    __syncthreads();

    int wn = t >> 3, ws = (t & 7) * 8;
    #pragma unroll
    for (int p = 0; p < 2; ++p) {
        int n = wn + p * 32;
        u16 pk[8];
        #pragma unroll
        for (int j = 0; j < 8; ++j) pk[j] = f2bf(tile[(ws + j) * 65 + n]);
        *(uint4*)(Wt + (size_t)(n0 + n) * D + k0 + ws) = *(uint4*)pk;
    }
}

// ---------- K1: project inputs, emit bf16 copies + g scalars ----------

__global__ __launch_bounds__(256) void prep(
    const float* __restrict__ hx, const float* __restrict__ h,
    u16* __restrict__ hx_bf, u16* __restrict__ h_bf,
    float* __restrict__ g_x, float* __restrict__ g_h) {
    __shared__ float sbuf[8];
    int b = blockIdx.x, t = threadIdx.x;
    size_t off = (size_t)b * D + t * 8;

    float xv[8], hv[8];
    load_f8(hx + off, xv);
    load_f8(h + off, hv);
    float s[2] = {0.f, 0.f};
    #pragma unroll
    for (int i = 0; i < 8; ++i) { s[0] += xv[i] * xv[i]; s[1] += hv[i] * hv[i]; }
    block_sums<2>(s, sbuf);

    float nx = sqrtf(fmaxf(s[0], MINN));
    float scx = (nx > MAXN) ? MAXN / nx : 1.0f;
    float nh = sqrtf(fmaxf(s[1], MINN));
    float sch = (nh > MAXN) ? MAXN / nh : 1.0f;
    #pragma unroll
    for (int i = 0; i < 8; ++i) { xv[i] *= scx; hv[i] *= sch; }
    store_bf8(hx_bf + off, xv);
    store_bf8(h_bf + off, hv);
    if (t == 0) {
        float xn = fminf(nx, MAXN), hn = fminf(nh, MAXN);
        g_x[b] = artanh_(xn) / xn;
        g_h[b] = artanh_(hn) / hn;
    }
}

// ---------- GEMM: C[M,N] = A[M,K](bf16) @ Wt[N,K](bf16)^T ----------
// BK=64, global_load_lds width-16 staging with XOR-swizzled segment order so
// the ds_read_b128 fragment reads hit all 32 banks (2 lanes/bank = free).
// CT = u16 (bf16 out) or float.

struct GemmBatch { const u16* A[4]; const u16* W[4]; void* C[4]; int koff[4]; };

template<int KLEN, typename CT>
__global__ __launch_bounds__(256) void gemm_bt(GemmBatch gb) {
    int z = blockIdx.z;
    const u16* __restrict__ A = gb.A[z];
    const u16* __restrict__ W = gb.W[z];
    CT* __restrict__ C = (CT*)gb.C[z];
    int koff = gb.koff[z];

    __shared__ u16 As[128 * 64];   // 16 KB
    __shared__ u16 Ws[128 * 64];   // 16 KB

    int t = threadIdx.x;
    int wave = t >> 6, lane = t & 63;
    int wr = wave >> 1, wc = wave & 1;       // 2x2 wave grid, each 64x64
    int quad = lane >> 4, l16 = lane & 15;
    int brow = blockIdx.y * 128, bcol = blockIdx.x * 128;

    // staging: wave handles rows [32*wave, 32*wave+32), 4 issues of 8 rows.
    int srow = 32 * wave + (lane >> 3);
    int sseg = (lane & 7) ^ ((lane >> 3) & 7);
    const u16* pa = A + (size_t)(brow + srow) * D + koff + sseg * 8;
    const u16* pw = W + (size_t)(bcol + srow) * D + koff + sseg * 8;
    u16* lbA = &As[wave * 2048];             // wave-uniform LDS bases
    u16* lbW = &Ws[wave * 2048];

    floatx4 acc[4][4];
    #pragma unroll
    for (int i = 0; i < 4; ++i)
        #pragma unroll
        for (int j = 0; j < 4; ++j)
            #pragma unroll
            for (int e = 0; e < 4; ++e) acc[i][j][e] = 0.f;

    int xsw = l16 & 7;                       // fragment-read swizzle term

    for (int k0 = 0; k0 < KLEN; k0 += 64) {
        __syncthreads();                     // everyone done reading prev tile
        #pragma unroll
        for (int i = 0; i < 4; ++i) {
            gl_lds16(pa + (size_t)(8 * i) * D + k0, lbA + i * 512);
            gl_lds16(pw + (size_t)(8 * i) * D + k0, lbW + i * 512);
        }
        __syncthreads();                     // vmcnt drained before barrier

        #pragma unroll
        for (int kk = 0; kk < 2; ++kk) {
            bf16x8 af[4], bfv[4];
            int ps = ((kk * 4 + quad) ^ xsw) * 8;
            #pragma unroll
            for (int i = 0; i < 4; ++i)
                af[i] = *(const bf16x8*)(&As[(wr * 64 + i * 16 + l16) * 64 + ps]);
            #pragma unroll
            for (int j = 0; j < 4; ++j)
                bfv[j] = *(const bf16x8*)(&Ws[(wc * 64 + j * 16 + l16) * 64 + ps]);
            #pragma unroll
            for (int i = 0; i < 4; ++i)
                #pragma unroll
                for (int j = 0; j < 4; ++j)
                    acc[i][j] = __builtin_amdgcn_mfma_f32_16x16x32_bf16(af[i], bfv[j], acc[i][j], 0, 0, 0);
        }
    }

    #pragma unroll
    for (int i = 0; i < 4; ++i) {
        #pragma unroll
        for (int j = 0; j < 4; ++j) {
            int row = brow + wr * 64 + i * 16 + quad * 4;
            int col = bcol + wc * 64 + j * 16 + l16;
            #pragma unroll
            for (int r = 0; r < 4; ++r) {
                float val = acc[i][j][r];
                if constexpr (sizeof(CT) == 2)
                    C[(size_t)(row + r) * D + col] = (CT)f2bf(val);
                else
                    C[(size_t)(row + r) * D + col] = (CT)val;
            }
        }
    }
}

// ---------- K4: fused middle (finish 4 matvecs, z, r, r_point_h) ----------

__global__ __launch_bounds__(256) void mid_kernel(
    const u16* __restrict__ c_wz, const u16* __restrict__ c_uz,
    const u16* __restrict__ c_wr, const u16* __restrict__ c_ur,
    const u16* __restrict__ h_bf,
    const float* __restrict__ g_x, const float* __restrict__ g_h,
    const float* __restrict__ b_z, const float* __restrict__ b_r,
    float* __restrict__ z_out, u16* __restrict__ uxr_out,
    u16* __restrict__ rph_bf, float* __restrict__ g_rph) {
    __shared__ float sbuf[24];
    int b = blockIdx.x, t = threadIdx.x;
    size_t off = (size_t)b * D + t * 8;
    int cbase = t * 8;

    float wz[8], uz[8], wr2[8], ur2[8], hp[8], bz[8], br[8];
    load_bf8(c_wz + off, wz);
    load_bf8(c_uz + off, uz);
    load_bf8(c_wr + off, wr2);
    load_bf8(c_ur + off, ur2);
    load_bf8(h_bf + off, hp);
    load_f8(b_z + cbase, bz);
    load_f8(b_r + cbase, br);

    float s[6] = {0, 0, 0, 0, 0, 0};
    #pragma unroll
    for (int i = 0; i < 8; ++i) {
        s[0] += wz[i] * wz[i];  s[1] += uz[i] * uz[i];
        s[2] += wr2[i] * wr2[i]; s[3] += ur2[i] * ur2[i];
        s[4] += bz[i] * bz[i];  s[5] += br[i] * br[i];
    }
    block_sums<6>(s, sbuf);
    float gh = g_h[b], gx = g_x[b];

    float cwz, nwz, cuz, nuz, cwr, nwr, cur, nur;
    mmm_finish(s[0], gh, &cwz, &nwz);
    mmm_finish(s[1], gx, &cuz, &nuz);
    mmm_finish(s[2], gh, &cwr, &nwr);
    mmm_finish(s[3], gx, &cur, &nur);
    #pragma unroll
    for (int i = 0; i < 8; ++i) {
        wz[i] *= cwz; uz[i] *= cuz; wr2[i] *= cwr; ur2[i] *= cur;
    }
    float sbz = s[4], sbr2 = s[5];

    // z-chain and r-chain mob_add #1 (batched duv)
    float d[2] = {0.f, 0.f};
    #pragma unroll
    for (int i = 0; i < 8; ++i) { d[0] += wz[i] * uz[i]; d[1] += wr2[i] * ur2[i]; }
    block_sums<2>(d, sbuf);
    float n1z = mob_apply(wz, uz, nwz * nwz, nuz * nuz, d[0]);
    float n1r = mob_apply(wr2, ur2, nwr * nwr, nur * nur, d[1]);

    // mob_add #2 (+bias, batched duv)
    d[0] = 0.f; d[1] = 0.f;
    #pragma unroll
    for (int i = 0; i < 8; ++i) { d[0] += wz[i] * bz[i]; d[1] += wr2[i] * br[i]; }
    block_sums<2>(d, sbuf);
    float n2z = mob_apply(wz, bz, n1z * n1z, sbz, d[0]);
    float n2r = mob_apply(wr2, br, n1r * n1r, sbr2, d[1]);

    float gz = artanh_(n2z) / n2z;
    float gr = artanh_(n2r) / n2r;
    float zz[8], v[8];
    float sv = 0.f;
    #pragma unroll
    for (int i = 0; i < 8; ++i) {
        zz[i] = sigmoid_(gz * wz[i]);
        float r = sigmoid_(gr * wr2[i]);
        v[i] = gh * hp[i] * r;            // log_map_zero(h) * r
        sv += v[i] * v[i];
    }
    store_f8(z_out + off, zz);
    block_sums<1>(&sv, sbuf);
    float nv = sqrtf(fmaxf(sv, MINN));
    float th = fminf(tanhf(nv), MAXN);
    float cr = th / nv;
    #pragma unroll
    for (int i = 0; i < 8; ++i) v[i] *= cr;
    store_bf8(rph_bf + off, v);
    store_bf8(uxr_out + off, ur2);        // finished UxR (reused for h_tilde)
    if (t == 0) g_rph[b] = artanh_(th) / th;
}

// ---------- K6: epilogue ----------

__global__ __launch_bounds__(256) void fin_kernel(
    const float* __restrict__ p0, const float* __restrict__ p1,
    const float* __restrict__ p2, const float* __restrict__ p3,
    const u16* __restrict__ uxr, const float* __restrict__ z_in,
    const u16* __restrict__ h_bf,
    const float* __restrict__ g_rph, const float* __restrict__ b_h,
    float* __restrict__ out) {
    __shared__ float sbuf[16];
    int b = blockIdx.x, t = threadIdx.x;
    size_t off = (size_t)b * D + t * 8;
    int cbase = t * 8;

    float wh[8], ux[8], zz[8], hp[8], bh[8], t0[8], t1[8];
    load_f8(p0 + off, wh);
    load_f8(p1 + off, t0);
    load_f8(p2 + off, t1);
    #pragma unroll
    for (int i = 0; i < 8; ++i) wh[i] += t0[i] + t1[i];
    load_f8(p3 + off, t0);
    #pragma unroll
    for (int i = 0; i < 8; ++i) wh[i] += t0[i];
    load_bf8(uxr + off, ux);
    load_f8(z_in + off, zz);
    load_bf8(h_bf + off, hp);
    load_f8(b_h + cbase, bh);

    float s[4] = {0, 0, 0, 0};
    #pragma unroll
    for (int i = 0; i < 8; ++i) {
        s[0] += wh[i] * wh[i]; s[1] += ux[i] * ux[i];
        s[2] += hp[i] * hp[i]; s[3] += bh[i] * bh[i];
    }
    block_sums<4>(s, sbuf);
    float swh = s[0], sux = s[1], shp = s[2], sbh = s[3];

    float cwh, nwh;
    mmm_finish(swh, g_rph[b], &cwh, &nwh);
    #pragma unroll
    for (int i = 0; i < 8; ++i) wh[i] *= cwh;

    // h_tilde = mob_add(mob_add(WhH, UxR), b_h)
    float d = 0.f;
    #pragma unroll
    for (int i = 0; i < 8; ++i) d += wh[i] * ux[i];
    block_sums<1>(&d, sbuf);
    float n1 = mob_apply(wh, ux, nwh * nwh, sux, d);

    d = 0.f;
    #pragma unroll
    for (int i = 0; i < 8; ++i) d += wh[i] * bh[i];
    block_sums<1>(&d, sbuf);
    float nht = mob_apply(wh, bh, n1 * n1, sbh, d);

    // minus = mob_add(-h_proj, h_tilde)
    #pragma unroll
    for (int i = 0; i < 8; ++i) ux[i] = -hp[i];   // reuse ux
    d = 0.f;
    #pragma unroll
    for (int i = 0; i < 8; ++i) d += ux[i] * wh[i];
    block_sums<1>(&d, sbuf);
    float nm = mob_apply(ux, wh, shp, nht * nht, d);

    // emz = exp_map_zero(log_map_zero(minus) * z)
    float lm = artanh_(nm) / nm;
    float sv = 0.f;
    #pragma unroll
    for (int i = 0; i < 8; ++i) {
        float v = lm * ux[i] * zz[i];
        ux[i] = v;
        sv += v * v;
    }
    block_sums<1>(&sv, sbuf);
    float nv = sqrtf(fmaxf(sv, MINN));
    float th = fminf(tanhf(nv), MAXN);
    float ce = th / nv;
    #pragma unroll
    for (int i = 0; i < 8; ++i) ux[i] *= ce;

    // new_h = mob_add(h_proj, emz)
    d = 0.f;
    #pragma unroll
    for (int i = 0; i < 8; ++i) d += hp[i] * ux[i];
    block_sums<1>(&d, sbuf);
    mob_apply(hp, ux, shp, th * th, d);
    store_f8(out + off, hp);
}

// ---------- launch ----------

extern "C" void kernel_launch(void* const* d_in, const int* in_sizes, int n_in,
                              void* d_out, int out_size, void* d_ws, size_t ws_size,
                              hipStream_t stream) {
    const float* hyp_x  = (const float*)d_in[0];
    const float* hidden = (const float*)d_in[1];
    const float* w_z = (const float*)d_in[2];
    const float* w_r = (const float*)d_in[3];
    const float* w_h = (const float*)d_in[4];
    const float* u_z = (const float*)d_in[5];
    const float* u_r = (const float*)d_in[6];
    const float* b_z = (const float*)d_in[7];
    const float* b_r = (const float*)d_in[8];
    const float* b_h = (const float*)d_in[9];
    float* out = (float*)d_out;

    int B = in_sizes[1] / D;   // 2048

    char* ws = (char*)d_ws;
    size_t o = 0;
    auto alloc = [&](size_t bytes) -> void* {
        void* p = ws + o;
        o += (bytes + 255) & ~(size_t)255;
        return p;
    };
    u16* wt[5];
    for (int i = 0; i < 5; ++i) wt[i] = (u16*)alloc((size_t)D * D * 2);
    u16* hx_bf = (u16*)alloc((size_t)B * D * 2);
    u16* h_bf  = (u16*)alloc((size_t)B * D * 2);
    float* g_x   = (float*)alloc((size_t)B * 4);
    float* g_h   = (float*)alloc((size_t)B * 4);
    float* g_rph = (float*)alloc((size_t)B * 4);
    u16* cz0 = (u16*)alloc((size_t)B * D * 2);   // G1 outputs, bf16
    u16* cz1 = (u16*)alloc((size_t)B * D * 2);
    u16* cz2 = (u16*)alloc((size_t)B * D * 2);
    u16* cz3 = (u16*)alloc((size_t)B * D * 2);
    float* p0 = (float*)alloc((size_t)B * D * 4);  // G2 K-partials, fp32
    float* p1 = (float*)alloc((size_t)B * D * 4);
    float* p2 = (float*)alloc((size_t)B * D * 4);
    float* p3 = (float*)alloc((size_t)B * D * 4);
    float* z_buf = (float*)alloc((size_t)B * D * 4);
    u16* uxr = (u16*)alloc((size_t)B * D * 2);
    u16* rph = (u16*)alloc((size_t)B * D * 2);

    // K0: transpose+convert 5 weight matrices (order: w_z,w_r,w_h,u_z,u_r)
    TransBatch tb;
    tb.W[0] = w_z; tb.W[1] = w_r; tb.W[2] = w_h; tb.W[3] = u_z; tb.W[4] = u_r;
    for (int i = 0; i < 5; ++i) tb.Wt[i] = wt[i];
    wtrans<<<dim3(D / 64, D / 64, 5), 256, 0, stream>>>(tb);

    // K1: projections
    prep<<<dim3(B), 256, 0, stream>>>(hyp_x, hidden, hx_bf, h_bf, g_x, g_h);

    // G1: cz0 = h@w_z, cz1 = x@u_z, cz2 = h@w_r, cz3 = x@u_r  (bf16 out)
    GemmBatch g1;
    g1.A[0] = h_bf;  g1.W[0] = wt[0]; g1.C[0] = cz0;
    g1.A[1] = hx_bf; g1.W[1] = wt[3]; g1.C[1] = cz1;
    g1.A[2] = h_bf;  g1.W[2] = wt[1]; g1.C[2] = cz2;
    g1.A[3] = hx_bf; g1.W[3] = wt[4]; g1.C[3] = cz3;
    for (int i = 0; i < 4; ++i) g1.koff[i] = 0;
    gemm_bt<2048, u16><<<dim3(D / 128, B / 128, 4), 256, 0, stream>>>(g1);

    // K4: middle fusion
    mid_kernel<<<dim3(B), 256, 0, stream>>>(cz0, cz1, cz2, cz3, h_bf, g_x, g_h,
                                            b_z, b_r, z_buf, uxr, rph, g_rph);

    // G2: 4-way K-split r_point_h @ w_h -> fp32 partials p0..p3
    GemmBatch g2;
    float* pb[4] = {p0, p1, p2, p3};
    for (int s = 0; s < 4; ++s) {
        g2.A[s] = rph; g2.W[s] = wt[2]; g2.C[s] = pb[s]; g2.koff[s] = s * 512;
    }
    gemm_bt<512, float><<<dim3(D / 128, B / 128, 4), 256, 0, stream>>>(g2);

    // K6: epilogue (sums the four K-partials of Wh @ r_point_h)
    fin_kernel<<<dim3(B), 256, 0, stream>>>(p0, p1, p2, p3, uxr, z_buf, h_bf,
                                            g_rph, b_h, out);
}

// Round 5
// 315.466 us; speedup vs baseline: 1.9792x; 1.0294x over previous
//
#include <hip/hip_runtime.h>
#include <hip/hip_bf16.h>
#include <math.h>

#define EPS 1e-5f
#define MAXN (1.0f - EPS)
#define MINN 1e-10f

constexpr int D = 2048;      // Dh == Din == 2048 for this problem

typedef unsigned short u16;
typedef __bf16 bf16x8 __attribute__((ext_vector_type(8)));
typedef float floatx4 __attribute__((ext_vector_type(4)));

// ---------- small helpers ----------

__device__ __forceinline__ u16 f2bf(float f) {
    union { float f; unsigned u; } v; v.f = f;
    unsigned r = v.u + 0x7FFFu + ((v.u >> 16) & 1u);   // RNE
    return (u16)(r >> 16);
}

__device__ __forceinline__ float bf2f(u16 b) {
    union { unsigned u; float f; } v; v.u = ((unsigned)b) << 16; return v.f;
}

// load 8 contiguous bf16 -> float[8] (one 16B load)
__device__ __forceinline__ void load_bf8(const u16* p, float* d) {
    uint4 r = *(const uint4*)p;
    unsigned w[4] = {r.x, r.y, r.z, r.w};
    #pragma unroll
    for (int i = 0; i < 4; ++i) {
        d[2 * i]     = bf2f((u16)(w[i] & 0xFFFFu));
        d[2 * i + 1] = bf2f((u16)(w[i] >> 16));
    }
}

// store float[8] -> 8 contiguous bf16 (one 16B store)
__device__ __forceinline__ void store_bf8(u16* p, const float* s) {
    u16 pk[8];
    #pragma unroll
    for (int i = 0; i < 8; ++i) pk[i] = f2bf(s[i]);
    *(uint4*)p = *(const uint4*)pk;
}

__device__ __forceinline__ void load_f8(const float* p, float* d) {
    *(float4*)(d)     = *(const float4*)(p);
    *(float4*)(d + 4) = *(const float4*)(p + 4);
}

__device__ __forceinline__ void store_f8(float* p, const float* s) {
    *(float4*)(p)     = *(const float4*)(s);
    *(float4*)(p + 4) = *(const float4*)(s + 4);
}

__device__ __forceinline__ float artanh_(float x) {
    x = fminf(fmaxf(x, -1.0f + EPS), 1.0f - EPS);
    return 0.5f * logf((1.0f + x) / (1.0f - x));
}

__device__ __forceinline__ float sigmoid_(float x) {
    return 1.0f / (1.0f + expf(-x));
}

// async global->LDS, 16 bytes/lane; lds base must be wave-uniform
__device__ __forceinline__ void gl_lds16(const u16* g, u16* l) {
    __builtin_amdgcn_global_load_lds(
        (const __attribute__((address_space(1))) unsigned int*)g,
        (__attribute__((address_space(3))) unsigned int*)l, 16, 0, 0);
}

// N simultaneous block-wide sums, ONE barrier pair. 256 threads / 4 waves.
template<int N>
__device__ __forceinline__ void block_sums(float* v, float* sbuf) {
    #pragma unroll
    for (int n = 0; n < N; ++n)
        #pragma unroll
        for (int off = 32; off >= 1; off >>= 1) v[n] += __shfl_xor(v[n], off, 64);
    int w = threadIdx.x >> 6;
    __syncthreads();                       // protect sbuf from previous call
    if ((threadIdx.x & 63) == 0) {
        #pragma unroll
        for (int n = 0; n < N; ++n) sbuf[w * N + n] = v[n];
    }
    __syncthreads();
    #pragma unroll
    for (int n = 0; n < N; ++n)
        v[n] = sbuf[n] + sbuf[N + n] + sbuf[2 * N + n] + sbuf[3 * N + n];
}

// finish mob_mat_mul: given |Mx|^2 and g = artanh(x_n)/x_n, return scale coef
// (out = coef * Mx_raw) and the output norm (post-proj).
__device__ __forceinline__ void mmm_finish(float sum2, float g, float* coef, float* onorm) {
    float mxn = sqrtf(fmaxf(sum2, MINN));
    float tt  = tanhf(mxn * g);
    float on  = fminf(tt, MAXN);
    *coef = on / mxn;
    *onorm = on;
}

// apply mob_add given duv already reduced. |num|^2 computed ANALYTICALLY:
// |cu*u + cv*v|^2 = cu^2 u2 + 2 cu cv duv + cv^2 v2  (no second reduction).
// u <- proj(mob_add(u,v)); returns post-proj norm.
__device__ __forceinline__ float mob_apply(float* u, const float* v,
                                           float u2, float v2, float duv) {
    float cu  = 1.f + 2.f * duv + v2;
    float cv  = 1.f - u2;
    float den = fmaxf(1.f + 2.f * duv + u2 * v2, MINN);
    float s2  = cu * cu * u2 + 2.f * cu * cv * duv + cv * cv * v2;
    float n   = sqrtf(fmaxf(s2 / (den * den), MINN));
    float sc  = ((n > MAXN) ? MAXN / n : 1.f) / den;
    #pragma unroll
    for (int i = 0; i < 8; ++i) u[i] = sc * (cu * u[i] + cv * v[i]);
    return fminf(n, MAXN);
}

// ---------- K0: merged weight-transpose (z<5) + input projection (z==5) ----------

struct PrepBatch {
    const float* W[5]; u16* Wt[5];
    const float* hx; const float* h;
    u16* hx_bf; u16* h_bf;
    float* g_x; float* g_h;
};

__global__ __launch_bounds__(256) void wtrans_prep(PrepBatch pb) {
    __shared__ float tile[64 * 65];        // transpose tile; first 8 reused as sbuf
    int t = threadIdx.x;

    if (blockIdx.z < 5) {
        const float* W = pb.W[blockIdx.z];
        u16* Wt = pb.Wt[blockIdx.z];
        int n0 = blockIdx.x * 64, k0 = blockIdx.y * 64;

        int lr = t >> 4, lc = (t & 15) * 4;
        #pragma unroll
        for (int p = 0; p < 4; ++p) {
            int r = lr + p * 16;
            float4 v = *(const float4*)(W + (size_t)(k0 + r) * D + n0 + lc);
            tile[r * 65 + lc + 0] = v.x;
            tile[r * 65 + lc + 1] = v.y;
            tile[r * 65 + lc + 2] = v.z;
            tile[r * 65 + lc + 3] = v.w;
        }
        __syncthreads();

        int wn = t >> 3, ws = (t & 7) * 8;
        #pragma unroll
        for (int p = 0; p < 2; ++p) {
            int n = wn + p * 32;
            u16 pk[8];
            #pragma unroll
            for (int j = 0; j < 8; ++j) pk[j] = f2bf(tile[(ws + j) * 65 + n]);
            *(uint4*)(Wt + (size_t)(n0 + n) * D + k0 + ws) = *(uint4*)pk;
        }
    } else {
        // projection: 1024 blocks here, each handles 2 rows
        int bid = blockIdx.y * (D / 64) + blockIdx.x;   // 0..1023
        for (int rr = 0; rr < 2; ++rr) {
            int b = bid * 2 + rr;
            size_t off = (size_t)b * D + t * 8;
            float xv[8], hv[8];
            load_f8(pb.hx + off, xv);
            load_f8(pb.h + off, hv);
            float s[2] = {0.f, 0.f};
            #pragma unroll
            for (int i = 0; i < 8; ++i) { s[0] += xv[i] * xv[i]; s[1] += hv[i] * hv[i]; }
            block_sums<2>(s, tile);

            float nx = sqrtf(fmaxf(s[0], MINN));
            float scx = (nx > MAXN) ? MAXN / nx : 1.0f;
            float nh = sqrtf(fmaxf(s[1], MINN));
            float sch = (nh > MAXN) ? MAXN / nh : 1.0f;
            #pragma unroll
            for (int i = 0; i < 8; ++i) { xv[i] *= scx; hv[i] *= sch; }
            store_bf8(pb.hx_bf + off, xv);
            store_bf8(pb.h_bf + off, hv);
            if (t == 0) {
                float xn = fminf(nx, MAXN), hn = fminf(nh, MAXN);
                pb.g_x[b] = artanh_(xn) / xn;
                pb.g_h[b] = artanh_(hn) / hn;
            }
        }
    }
}

// ---------- GEMM: C[M,N] = A[M,K](bf16) @ Wt[N,K](bf16)^T ----------
// BK=64, global_load_lds width-16 staging with XOR-swizzled segment order so
// the ds_read_b128 fragment reads hit all 32 banks (2 lanes/bank = free).
// CT = u16 (bf16 out) or float.

struct GemmBatch { const u16* A[4]; const u16* W[4]; void* C[4]; int koff[4]; };

template<int KLEN, typename CT>
__global__ __launch_bounds__(256) void gemm_bt(GemmBatch gb) {
    int z = blockIdx.z;
    const u16* __restrict__ A = gb.A[z];
    const u16* __restrict__ W = gb.W[z];
    CT* __restrict__ C = (CT*)gb.C[z];
    int koff = gb.koff[z];

    __shared__ u16 As[128 * 64];   // 16 KB
    __shared__ u16 Ws[128 * 64];   // 16 KB

    int t = threadIdx.x;
    int wave = t >> 6, lane = t & 63;
    int wr = wave >> 1, wc = wave & 1;       // 2x2 wave grid, each 64x64
    int quad = lane >> 4, l16 = lane & 15;
    int brow = blockIdx.y * 128, bcol = blockIdx.x * 128;

    // staging: wave handles rows [32*wave, 32*wave+32), 4 issues of 8 rows.
    int srow = 32 * wave + (lane >> 3);
    int sseg = (lane & 7) ^ ((lane >> 3) & 7);
    const u16* pa = A + (size_t)(brow + srow) * D + koff + sseg * 8;
    const u16* pw = W + (size_t)(bcol + srow) * D + koff + sseg * 8;
    u16* lbA = &As[wave * 2048];             // wave-uniform LDS bases
    u16* lbW = &Ws[wave * 2048];

    floatx4 acc[4][4];
    #pragma unroll
    for (int i = 0; i < 4; ++i)
        #pragma unroll
        for (int j = 0; j < 4; ++j)
            #pragma unroll
            for (int e = 0; e < 4; ++e) acc[i][j][e] = 0.f;

    int xsw = l16 & 7;                       // fragment-read swizzle term

    for (int k0 = 0; k0 < KLEN; k0 += 64) {
        __syncthreads();                     // everyone done reading prev tile
        #pragma unroll
        for (int i = 0; i < 4; ++i) {
            gl_lds16(pa + (size_t)(8 * i) * D + k0, lbA + i * 512);
            gl_lds16(pw + (size_t)(8 * i) * D + k0, lbW + i * 512);
        }
        __syncthreads();                     // vmcnt drained before barrier

        #pragma unroll
        for (int kk = 0; kk < 2; ++kk) {
            bf16x8 af[4], bfv[4];
            int ps = ((kk * 4 + quad) ^ xsw) * 8;
            #pragma unroll
            for (int i = 0; i < 4; ++i)
                af[i] = *(const bf16x8*)(&As[(wr * 64 + i * 16 + l16) * 64 + ps]);
            #pragma unroll
            for (int j = 0; j < 4; ++j)
                bfv[j] = *(const bf16x8*)(&Ws[(wc * 64 + j * 16 + l16) * 64 + ps]);
            #pragma unroll
            for (int i = 0; i < 4; ++i)
                #pragma unroll
                for (int j = 0; j < 4; ++j)
                    acc[i][j] = __builtin_amdgcn_mfma_f32_16x16x32_bf16(af[i], bfv[j], acc[i][j], 0, 0, 0);
        }
    }

    #pragma unroll
    for (int i = 0; i < 4; ++i) {
        #pragma unroll
        for (int j = 0; j < 4; ++j) {
            int row = brow + wr * 64 + i * 16 + quad * 4;
            int col = bcol + wc * 64 + j * 16 + l16;
            #pragma unroll
            for (int r = 0; r < 4; ++r) {
                float val = acc[i][j][r];
                if constexpr (sizeof(CT) == 2)
                    C[(size_t)(row + r) * D + col] = (CT)f2bf(val);
                else
                    C[(size_t)(row + r) * D + col] = (CT)val;
            }
        }
    }
}

// ---------- K4: fused middle (finish 4 matvecs, z, r, r_point_h) ----------

__global__ __launch_bounds__(256) void mid_kernel(
    const u16* __restrict__ c_wz, const u16* __restrict__ c_uz,
    const u16* __restrict__ c_wr, const u16* __restrict__ c_ur,
    const u16* __restrict__ h_bf,
    const float* __restrict__ g_x, const float* __restrict__ g_h,
    const float* __restrict__ b_z, const float* __restrict__ b_r,
    u16* __restrict__ z_out, u16* __restrict__ uxr_out,
    u16* __restrict__ rph_bf, float* __restrict__ g_rph) {
    __shared__ float sbuf[24];
    int b = blockIdx.x, t = threadIdx.x;
    size_t off = (size_t)b * D + t * 8;
    int cbase = t * 8;

    float wz[8], uz[8], wr2[8], ur2[8], hp[8], bz[8], br[8];
    load_bf8(c_wz + off, wz);
    load_bf8(c_uz + off, uz);
    load_bf8(c_wr + off, wr2);
    load_bf8(c_ur + off, ur2);
    load_bf8(h_bf + off, hp);
    load_f8(b_z + cbase, bz);
    load_f8(b_r + cbase, br);

    float s[6] = {0, 0, 0, 0, 0, 0};
    #pragma unroll
    for (int i = 0; i < 8; ++i) {
        s[0] += wz[i] * wz[i];  s[1] += uz[i] * uz[i];
        s[2] += wr2[i] * wr2[i]; s[3] += ur2[i] * ur2[i];
        s[4] += bz[i] * bz[i];  s[5] += br[i] * br[i];
    }
    block_sums<6>(s, sbuf);
    float gh = g_h[b], gx = g_x[b];

    float cwz, nwz, cuz, nuz, cwr, nwr, cur, nur;
    mmm_finish(s[0], gh, &cwz, &nwz);
    mmm_finish(s[1], gx, &cuz, &nuz);
    mmm_finish(s[2], gh, &cwr, &nwr);
    mmm_finish(s[3], gx, &cur, &nur);
    #pragma unroll
    for (int i = 0; i < 8; ++i) {
        wz[i] *= cwz; uz[i] *= cuz; wr2[i] *= cwr; ur2[i] *= cur;
    }
    float sbz = s[4], sbr2 = s[5];

    // z-chain and r-chain mob_add #1 (batched duv)
    float d[2] = {0.f, 0.f};
    #pragma unroll
    for (int i = 0; i < 8; ++i) { d[0] += wz[i] * uz[i]; d[1] += wr2[i] * ur2[i]; }
    block_sums<2>(d, sbuf);
    float n1z = mob_apply(wz, uz, nwz * nwz, nuz * nuz, d[0]);
    float n1r = mob_apply(wr2, ur2, nwr * nwr, nur * nur, d[1]);

    // mob_add #2 (+bias, batched duv)
    d[0] = 0.f; d[1] = 0.f;
    #pragma unroll
    for (int i = 0; i < 8; ++i) { d[0] += wz[i] * bz[i]; d[1] += wr2[i] * br[i]; }
    block_sums<2>(d, sbuf);
    float n2z = mob_apply(wz, bz, n1z * n1z, sbz, d[0]);
    float n2r = mob_apply(wr2, br, n1r * n1r, sbr2, d[1]);

    float gz = artanh_(n2z) / n2z;
    float gr = artanh_(n2r) / n2r;
    float zz[8], v[8];
    float sv = 0.f;
    #pragma unroll
    for (int i = 0; i < 8; ++i) {
        zz[i] = sigmoid_(gz * wz[i]);
        float r = sigmoid_(gr * wr2[i]);
        v[i] = gh * hp[i] * r;            // log_map_zero(h) * r
        sv += v[i] * v[i];
    }
    store_bf8(z_out + off, zz);
    block_sums<1>(&sv, sbuf);
    float nv = sqrtf(fmaxf(sv, MINN));
    float th = fminf(tanhf(nv), MAXN);
    float cr = th / nv;
    #pragma unroll
    for (int i = 0; i < 8; ++i) v[i] *= cr;
    store_bf8(rph_bf + off, v);
    store_bf8(uxr_out + off, ur2);        // finished UxR (reused for h_tilde)
    if (t == 0) g_rph[b] = artanh_(th) / th;
}

// ---------- K6: epilogue ----------

__global__ __launch_bounds__(256) void fin_kernel(
    const u16* __restrict__ p0, const u16* __restrict__ p1,
    const u16* __restrict__ p2, const u16* __restrict__ p3,
    const u16* __restrict__ uxr, const u16* __restrict__ z_in,
    const u16* __restrict__ h_bf,
    const float* __restrict__ g_rph, const float* __restrict__ b_h,
    float* __restrict__ out) {
    __shared__ float sbuf[16];
    int b = blockIdx.x, t = threadIdx.x;
    size_t off = (size_t)b * D + t * 8;
    int cbase = t * 8;

    float wh[8], ux[8], zz[8], hp[8], bh[8], t0[8], t1[8];
    load_bf8(p0 + off, wh);
    load_bf8(p1 + off, t0);
    load_bf8(p2 + off, t1);
    #pragma unroll
    for (int i = 0; i < 8; ++i) wh[i] += t0[i] + t1[i];
    load_bf8(p3 + off, t0);
    #pragma unroll
    for (int i = 0; i < 8; ++i) wh[i] += t0[i];
    load_bf8(uxr + off, ux);
    load_bf8(z_in + off, zz);
    load_bf8(h_bf + off, hp);
    load_f8(b_h + cbase, bh);

    float s[4] = {0, 0, 0, 0};
    #pragma unroll
    for (int i = 0; i < 8; ++i) {
        s[0] += wh[i] * wh[i]; s[1] += ux[i] * ux[i];
        s[2] += hp[i] * hp[i]; s[3] += bh[i] * bh[i];
    }
    block_sums<4>(s, sbuf);
    float swh = s[0], sux = s[1], shp = s[2], sbh = s[3];

    float cwh, nwh;
    mmm_finish(swh, g_rph[b], &cwh, &nwh);
    #pragma unroll
    for (int i = 0; i < 8; ++i) wh[i] *= cwh;

    // h_tilde = mob_add(mob_add(WhH, UxR), b_h)
    float d = 0.f;
    #pragma unroll
    for (int i = 0; i < 8; ++i) d += wh[i] * ux[i];
    block_sums<1>(&d, sbuf);
    float n1 = mob_apply(wh, ux, nwh * nwh, sux, d);

    d = 0.f;
    #pragma unroll
    for (int i = 0; i < 8; ++i) d += wh[i] * bh[i];
    block_sums<1>(&d, sbuf);
    float nht = mob_apply(wh, bh, n1 * n1, sbh, d);

    // minus = mob_add(-h_proj, h_tilde)
    #pragma unroll
    for (int i = 0; i < 8; ++i) ux[i] = -hp[i];   // reuse ux
    d = 0.f;
    #pragma unroll
    for (int i = 0; i < 8; ++i) d += ux[i] * wh[i];
    block_sums<1>(&d, sbuf);
    float nm = mob_apply(ux, wh, shp, nht * nht, d);

    // emz = exp_map_zero(log_map_zero(minus) * z)
    float lm = artanh_(nm) / nm;
    float sv = 0.f;
    #pragma unroll
    for (int i = 0; i < 8; ++i) {
        float v = lm * ux[i] * zz[i];
        ux[i] = v;
        sv += v * v;
    }
    block_sums<1>(&sv, sbuf);
    float nv = sqrtf(fmaxf(sv, MINN));
    float th = fminf(tanhf(nv), MAXN);
    float ce = th / nv;
    #pragma unroll
    for (int i = 0; i < 8; ++i) ux[i] *= ce;

    // new_h = mob_add(h_proj, emz)
    d = 0.f;
    #pragma unroll
    for (int i = 0; i < 8; ++i) d += hp[i] * ux[i];
    block_sums<1>(&d, sbuf);
    mob_apply(hp, ux, shp, th * th, d);
    store_f8(out + off, hp);
}

// ---------- launch ----------

extern "C" void kernel_launch(void* const* d_in, const int* in_sizes, int n_in,
                              void* d_out, int out_size, void* d_ws, size_t ws_size,
                              hipStream_t stream) {
    const float* hyp_x  = (const float*)d_in[0];
    const float* hidden = (const float*)d_in[1];
    const float* w_z = (const float*)d_in[2];
    const float* w_r = (const float*)d_in[3];
    const float* w_h = (const float*)d_in[4];
    const float* u_z = (const float*)d_in[5];
    const float* u_r = (const float*)d_in[6];
    const float* b_z = (const float*)d_in[7];
    const float* b_r = (const float*)d_in[8];
    const float* b_h = (const float*)d_in[9];
    float* out = (float*)d_out;

    int B = in_sizes[1] / D;   // 2048

    char* ws = (char*)d_ws;
    size_t o = 0;
    auto alloc = [&](size_t bytes) -> void* {
        void* p = ws + o;
        o += (bytes + 255) & ~(size_t)255;
        return p;
    };
    u16* wt[5];
    for (int i = 0; i < 5; ++i) wt[i] = (u16*)alloc((size_t)D * D * 2);
    u16* hx_bf = (u16*)alloc((size_t)B * D * 2);
    u16* h_bf  = (u16*)alloc((size_t)B * D * 2);
    float* g_x   = (float*)alloc((size_t)B * 4);
    float* g_h   = (float*)alloc((size_t)B * 4);
    float* g_rph = (float*)alloc((size_t)B * 4);
    u16* cz0 = (u16*)alloc((size_t)B * D * 2);   // G1 outputs, bf16
    u16* cz1 = (u16*)alloc((size_t)B * D * 2);
    u16* cz2 = (u16*)alloc((size_t)B * D * 2);
    u16* cz3 = (u16*)alloc((size_t)B * D * 2);
    u16* p0 = (u16*)alloc((size_t)B * D * 2);    // G2 K-partials, bf16
    u16* p1 = (u16*)alloc((size_t)B * D * 2);
    u16* p2 = (u16*)alloc((size_t)B * D * 2);
    u16* p3 = (u16*)alloc((size_t)B * D * 2);
    u16* z_buf = (u16*)alloc((size_t)B * D * 2);
    u16* uxr = (u16*)alloc((size_t)B * D * 2);
    u16* rph = (u16*)alloc((size_t)B * D * 2);

    // K0: merged transpose (z<5: w_z,w_r,w_h,u_z,u_r) + projection (z==5)
    PrepBatch pb;
    pb.W[0] = w_z; pb.W[1] = w_r; pb.W[2] = w_h; pb.W[3] = u_z; pb.W[4] = u_r;
    for (int i = 0; i < 5; ++i) pb.Wt[i] = wt[i];
    pb.hx = hyp_x; pb.h = hidden;
    pb.hx_bf = hx_bf; pb.h_bf = h_bf;
    pb.g_x = g_x; pb.g_h = g_h;
    wtrans_prep<<<dim3(D / 64, D / 64, 6), 256, 0, stream>>>(pb);

    // G1: cz0 = h@w_z, cz1 = x@u_z, cz2 = h@w_r, cz3 = x@u_r  (bf16 out)
    GemmBatch g1;
    g1.A[0] = h_bf;  g1.W[0] = wt[0]; g1.C[0] = cz0;
    g1.A[1] = hx_bf; g1.W[1] = wt[3]; g1.C[1] = cz1;
    g1.A[2] = h_bf;  g1.W[2] = wt[1]; g1.C[2] = cz2;
    g1.A[3] = hx_bf; g1.W[3] = wt[4]; g1.C[3] = cz3;
    for (int i = 0; i < 4; ++i) g1.koff[i] = 0;
    gemm_bt<2048, u16><<<dim3(D / 128, B / 128, 4), 256, 0, stream>>>(g1);

    // K4: middle fusion
    mid_kernel<<<dim3(B), 256, 0, stream>>>(cz0, cz1, cz2, cz3, h_bf, g_x, g_h,
                                            b_z, b_r, z_buf, uxr, rph, g_rph);

    // G2: 4-way K-split r_point_h @ w_h -> bf16 partials p0..p3
    GemmBatch g2;
    u16* pbuf[4] = {p0, p1, p2, p3};
    for (int s = 0; s < 4; ++s) {
        g2.A[s] = rph; g2.W[s] = wt[2]; g2.C[s] = pbuf[s]; g2.koff[s] = s * 512;
    }
    gemm_bt<512, u16><<<dim3(D / 128, B / 128, 4), 256, 0, stream>>>(g2);

    // K6: epilogue (sums the four K-partials of Wh @ r_point_h)
    fin_kernel<<<dim3(B), 256, 0, stream>>>(p0, p1, p2, p3, uxr, z_buf, h_bf,
                                            g_rph, b_h, out);
}

// Round 6
// 312.238 us; speedup vs baseline: 1.9996x; 1.0103x over previous
//
#include <hip/hip_runtime.h>
#include <hip/hip_bf16.h>
#include <math.h>

#define EPS 1e-5f
#define MAXN (1.0f - EPS)
#define MINN 1e-10f

constexpr int D = 2048;      // Dh == Din == 2048 for this problem

typedef unsigned short u16;
typedef __bf16 bf16x8 __attribute__((ext_vector_type(8)));
typedef float floatx4 __attribute__((ext_vector_type(4)));

// ---------- small helpers ----------

__device__ __forceinline__ u16 f2bf(float f) {
    union { float f; unsigned u; } v; v.f = f;
    unsigned r = v.u + 0x7FFFu + ((v.u >> 16) & 1u);   // RNE
    return (u16)(r >> 16);
}

__device__ __forceinline__ float bf2f(u16 b) {
    union { unsigned u; float f; } v; v.u = ((unsigned)b) << 16; return v.f;
}

// load 8 contiguous bf16 -> float[8] (one 16B load)
__device__ __forceinline__ void load_bf8(const u16* p, float* d) {
    uint4 r = *(const uint4*)p;
    unsigned w[4] = {r.x, r.y, r.z, r.w};
    #pragma unroll
    for (int i = 0; i < 4; ++i) {
        d[2 * i]     = bf2f((u16)(w[i] & 0xFFFFu));
        d[2 * i + 1] = bf2f((u16)(w[i] >> 16));
    }
}

// store float[8] -> 8 contiguous bf16 (one 16B store)
__device__ __forceinline__ void store_bf8(u16* p, const float* s) {
    u16 pk[8];
    #pragma unroll
    for (int i = 0; i < 8; ++i) pk[i] = f2bf(s[i]);
    *(uint4*)p = *(const uint4*)pk;
}

__device__ __forceinline__ void load_f8(const float* p, float* d) {
    *(float4*)(d)     = *(const float4*)(p);
    *(float4*)(d + 4) = *(const float4*)(p + 4);
}

__device__ __forceinline__ void store_f8(float* p, const float* s) {
    *(float4*)(p)     = *(const float4*)(s);
    *(float4*)(p + 4) = *(const float4*)(s + 4);
}

__device__ __forceinline__ float artanh_(float x) {
    x = fminf(fmaxf(x, -1.0f + EPS), 1.0f - EPS);
    return 0.5f * logf((1.0f + x) / (1.0f - x));
}

__device__ __forceinline__ float sigmoid_(float x) {
    return 1.0f / (1.0f + expf(-x));
}

// async global->LDS, 16 bytes/lane; lds base must be wave-uniform
__device__ __forceinline__ void gl_lds16(const u16* g, u16* l) {
    __builtin_amdgcn_global_load_lds(
        (const __attribute__((address_space(1))) unsigned int*)g,
        (__attribute__((address_space(3))) unsigned int*)l, 16, 0, 0);
}

// N simultaneous block-wide sums, ONE barrier pair. 256 threads / 4 waves.
template<int N>
__device__ __forceinline__ void block_sums(float* v, float* sbuf) {
    #pragma unroll
    for (int n = 0; n < N; ++n)
        #pragma unroll
        for (int off = 32; off >= 1; off >>= 1) v[n] += __shfl_xor(v[n], off, 64);
    int w = threadIdx.x >> 6;
    __syncthreads();                       // protect sbuf from previous call
    if ((threadIdx.x & 63) == 0) {
        #pragma unroll
        for (int n = 0; n < N; ++n) sbuf[w * N + n] = v[n];
    }
    __syncthreads();
    #pragma unroll
    for (int n = 0; n < N; ++n)
        v[n] = sbuf[n] + sbuf[N + n] + sbuf[2 * N + n] + sbuf[3 * N + n];
}

// finish mob_mat_mul: given |Mx|^2 and g = artanh(x_n)/x_n, return scale coef
// (out = coef * Mx_raw) and the output norm (post-proj).
__device__ __forceinline__ void mmm_finish(float sum2, float g, float* coef, float* onorm) {
    float mxn = sqrtf(fmaxf(sum2, MINN));
    float tt  = tanhf(mxn * g);
    float on  = fminf(tt, MAXN);
    *coef = on / mxn;
    *onorm = on;
}

// apply mob_add given duv already reduced. |num|^2 computed ANALYTICALLY:
// |cu*u + cv*v|^2 = cu^2 u2 + 2 cu cv duv + cv^2 v2  (no second reduction).
// u <- proj(mob_add(u,v)); returns post-proj norm.
__device__ __forceinline__ float mob_apply(float* u, const float* v,
                                           float u2, float v2, float duv) {
    float cu  = 1.f + 2.f * duv + v2;
    float cv  = 1.f - u2;
    float den = fmaxf(1.f + 2.f * duv + u2 * v2, MINN);
    float s2  = cu * cu * u2 + 2.f * cu * cv * duv + cv * cv * v2;
    float n   = sqrtf(fmaxf(s2 / (den * den), MINN));
    float sc  = ((n > MAXN) ? MAXN / n : 1.f) / den;
    #pragma unroll
    for (int i = 0; i < 8; ++i) u[i] = sc * (cu * u[i] + cv * v[i]);
    return fminf(n, MAXN);
}

// shared transpose-tile helper: one 64x64 f32->bf16T tile through LDS
__device__ __forceinline__ void trans_tile(const float* W, u16* Wt,
                                           int n0, int k0, float* tile) {
    int t = threadIdx.x;
    int lr = t >> 4, lc = (t & 15) * 4;
    #pragma unroll
    for (int p = 0; p < 4; ++p) {
        int r = lr + p * 16;
        float4 v = *(const float4*)(W + (size_t)(k0 + r) * D + n0 + lc);
        tile[r * 65 + lc + 0] = v.x;
        tile[r * 65 + lc + 1] = v.y;
        tile[r * 65 + lc + 2] = v.z;
        tile[r * 65 + lc + 3] = v.w;
    }
    __syncthreads();
    int wn = t >> 3, ws = (t & 7) * 8;
    #pragma unroll
    for (int p = 0; p < 2; ++p) {
        int n = wn + p * 32;
        u16 pk[8];
        #pragma unroll
        for (int j = 0; j < 8; ++j) pk[j] = f2bf(tile[(ws + j) * 65 + n]);
        *(uint4*)(Wt + (size_t)(n0 + n) * D + k0 + ws) = *(uint4*)pk;
    }
}

// ---------- K0: transpose 4 G1-weights (z<4) + input projection (z==4) ----------

struct PrepBatch {
    const float* W[4]; u16* Wt[4];
    const float* hx; const float* h;
    u16* hx_bf; u16* h_bf;
    float* g_x; float* g_h;
};

__global__ __launch_bounds__(256) void wtrans_prep(PrepBatch pb) {
    __shared__ float tile[64 * 65];        // transpose tile; first 8 reused as sbuf
    int t = threadIdx.x;

    if (blockIdx.z < 4) {
        trans_tile(pb.W[blockIdx.z], pb.Wt[blockIdx.z],
                   blockIdx.x * 64, blockIdx.y * 64, tile);
    } else {
        // projection: 1024 blocks here, each handles 2 rows
        int bid = blockIdx.y * (D / 64) + blockIdx.x;   // 0..1023
        for (int rr = 0; rr < 2; ++rr) {
            int b = bid * 2 + rr;
            size_t off = (size_t)b * D + t * 8;
            float xv[8], hv[8];
            load_f8(pb.hx + off, xv);
            load_f8(pb.h + off, hv);
            float s[2] = {0.f, 0.f};
            #pragma unroll
            for (int i = 0; i < 8; ++i) { s[0] += xv[i] * xv[i]; s[1] += hv[i] * hv[i]; }
            block_sums<2>(s, tile);

            float nx = sqrtf(fmaxf(s[0], MINN));
            float scx = (nx > MAXN) ? MAXN / nx : 1.0f;
            float nh = sqrtf(fmaxf(s[1], MINN));
            float sch = (nh > MAXN) ? MAXN / nh : 1.0f;
            #pragma unroll
            for (int i = 0; i < 8; ++i) { xv[i] *= scx; hv[i] *= sch; }
            store_bf8(pb.hx_bf + off, xv);
            store_bf8(pb.h_bf + off, hv);
            if (t == 0) {
                float xn = fminf(nx, MAXN), hn = fminf(nh, MAXN);
                pb.g_x[b] = artanh_(xn) / xn;
                pb.g_h[b] = artanh_(hn) / hn;
            }
        }
    }
}

// ---------- GEMM core (m97-style, BK=64, swizzled global_load_lds) ----------
// C[M,N] = A[M,K](bf16) @ Wt[N,K](bf16)^T. CT = u16 (bf16 out) or float.

template<int KLEN, typename CT>
__device__ __forceinline__ void gemm_body(const u16* __restrict__ A,
                                          const u16* __restrict__ W,
                                          CT* __restrict__ C, int koff,
                                          u16* As, u16* Ws) {
    int t = threadIdx.x;
    int wave = t >> 6, lane = t & 63;
    int wr = wave >> 1, wc = wave & 1;       // 2x2 wave grid, each 64x64
    int quad = lane >> 4, l16 = lane & 15;
    int brow = blockIdx.y * 128, bcol = blockIdx.x * 128;

    // staging: wave handles rows [32*wave, 32*wave+32), 4 issues of 8 rows.
    int srow = 32 * wave + (lane >> 3);
    int sseg = (lane & 7) ^ ((lane >> 3) & 7);
    const u16* pa = A + (size_t)(brow + srow) * D + koff + sseg * 8;
    const u16* pw = W + (size_t)(bcol + srow) * D + koff + sseg * 8;
    u16* lbA = &As[wave * 2048];             // wave-uniform LDS bases
    u16* lbW = &Ws[wave * 2048];

    floatx4 acc[4][4];
    #pragma unroll
    for (int i = 0; i < 4; ++i)
        #pragma unroll
        for (int j = 0; j < 4; ++j)
            #pragma unroll
            for (int e = 0; e < 4; ++e) acc[i][j][e] = 0.f;

    int xsw = l16 & 7;                       // fragment-read swizzle term

    for (int k0 = 0; k0 < KLEN; k0 += 64) {
        __syncthreads();                     // everyone done reading prev tile
        #pragma unroll
        for (int i = 0; i < 4; ++i) {
            gl_lds16(pa + (size_t)(8 * i) * D + k0, lbA + i * 512);
            gl_lds16(pw + (size_t)(8 * i) * D + k0, lbW + i * 512);
        }
        __syncthreads();                     // vmcnt drained before barrier

        #pragma unroll
        for (int kk = 0; kk < 2; ++kk) {
            bf16x8 af[4], bfv[4];
            int ps = ((kk * 4 + quad) ^ xsw) * 8;
            #pragma unroll
            for (int i = 0; i < 4; ++i)
                af[i] = *(const bf16x8*)(&As[(wr * 64 + i * 16 + l16) * 64 + ps]);
            #pragma unroll
            for (int j = 0; j < 4; ++j)
                bfv[j] = *(const bf16x8*)(&Ws[(wc * 64 + j * 16 + l16) * 64 + ps]);
            #pragma unroll
            for (int i = 0; i < 4; ++i)
                #pragma unroll
                for (int j = 0; j < 4; ++j)
                    acc[i][j] = __builtin_amdgcn_mfma_f32_16x16x32_bf16(af[i], bfv[j], acc[i][j], 0, 0, 0);
        }
    }

    #pragma unroll
    for (int i = 0; i < 4; ++i) {
        #pragma unroll
        for (int j = 0; j < 4; ++j) {
            int row = brow + wr * 64 + i * 16 + quad * 4;
            int col = bcol + wc * 64 + j * 16 + l16;
            #pragma unroll
            for (int r = 0; r < 4; ++r) {
                float val = acc[i][j][r];
                if constexpr (sizeof(CT) == 2)
                    C[(size_t)(row + r) * D + col] = (CT)f2bf(val);
                else
                    C[(size_t)(row + r) * D + col] = (CT)val;
            }
        }
    }
}

// ---------- G1: 4 GEMMs (z<4) + w_h transpose (z==4, hidden under GEMM BW) ----------

struct G1Batch {
    const u16* A[4]; const u16* W[4]; u16* C[4];
    const float* Wh; u16* WhT;
};

__global__ __launch_bounds__(256) void g1_kernel(G1Batch gb) {
    __shared__ u16 smem[128 * 64 * 2];     // 32 KB: GEMM tiles / transpose tile
    if (blockIdx.z < 4) {
        gemm_body<2048, u16>(gb.A[blockIdx.z], gb.W[blockIdx.z], gb.C[blockIdx.z],
                             0, smem, smem + 128 * 64);
    } else {
        float* tile = (float*)smem;        // 64*65*4 = 16.6 KB, fits
        #pragma unroll
        for (int ti = 0; ti < 4; ++ti) {
            if (ti) __syncthreads();       // protect tile reuse
            int n0 = (blockIdx.x * 2 + (ti & 1)) * 64;
            int k0 = (blockIdx.y * 2 + (ti >> 1)) * 64;
            trans_tile(gb.Wh, gb.WhT, n0, k0, tile);
        }
    }
}

// ---------- G2: 2-way K-split GEMM ----------

struct GemmBatch { const u16* A[2]; const u16* W[2]; u16* C[2]; int koff[2]; };

__global__ __launch_bounds__(256) void g2_kernel(GemmBatch gb) {
    __shared__ u16 smem[128 * 64 * 2];
    int z = blockIdx.z;
    gemm_body<1024, u16>(gb.A[z], gb.W[z], gb.C[z], gb.koff[z],
                         smem, smem + 128 * 64);
}

// ---------- K4: fused middle (finish 4 matvecs, z, r, r_point_h) ----------

__global__ __launch_bounds__(256) void mid_kernel(
    const u16* __restrict__ c_wz, const u16* __restrict__ c_uz,
    const u16* __restrict__ c_wr, const u16* __restrict__ c_ur,
    const u16* __restrict__ h_bf,
    const float* __restrict__ g_x, const float* __restrict__ g_h,
    const float* __restrict__ b_z, const float* __restrict__ b_r,
    u16* __restrict__ z_out, u16* __restrict__ uxr_out,
    u16* __restrict__ rph_bf, float* __restrict__ g_rph) {
    __shared__ float sbuf[24];
    int b = blockIdx.x, t = threadIdx.x;
    size_t off = (size_t)b * D + t * 8;
    int cbase = t * 8;

    float wz[8], uz[8], wr2[8], ur2[8], hp[8], bz[8], br[8];
    load_bf8(c_wz + off, wz);
    load_bf8(c_uz + off, uz);
    load_bf8(c_wr + off, wr2);
    load_bf8(c_ur + off, ur2);
    load_bf8(h_bf + off, hp);
    load_f8(b_z + cbase, bz);
    load_f8(b_r + cbase, br);

    float s[6] = {0, 0, 0, 0, 0, 0};
    #pragma unroll
    for (int i = 0; i < 8; ++i) {
        s[0] += wz[i] * wz[i];  s[1] += uz[i] * uz[i];
        s[2] += wr2[i] * wr2[i]; s[3] += ur2[i] * ur2[i];
        s[4] += bz[i] * bz[i];  s[5] += br[i] * br[i];
    }
    block_sums<6>(s, sbuf);
    float gh = g_h[b], gx = g_x[b];

    float cwz, nwz, cuz, nuz, cwr, nwr, cur, nur;
    mmm_finish(s[0], gh, &cwz, &nwz);
    mmm_finish(s[1], gx, &cuz, &nuz);
    mmm_finish(s[2], gh, &cwr, &nwr);
    mmm_finish(s[3], gx, &cur, &nur);
    #pragma unroll
    for (int i = 0; i < 8; ++i) {
        wz[i] *= cwz; uz[i] *= cuz; wr2[i] *= cwr; ur2[i] *= cur;
    }
    float sbz = s[4], sbr2 = s[5];

    // z-chain and r-chain mob_add #1 (batched duv)
    float d[2] = {0.f, 0.f};
    #pragma unroll
    for (int i = 0; i < 8; ++i) { d[0] += wz[i] * uz[i]; d[1] += wr2[i] * ur2[i]; }
    block_sums<2>(d, sbuf);
    float n1z = mob_apply(wz, uz, nwz * nwz, nuz * nuz, d[0]);
    float n1r = mob_apply(wr2, ur2, nwr * nwr, nur * nur, d[1]);

    // mob_add #2 (+bias, batched duv)
    d[0] = 0.f; d[1] = 0.f;
    #pragma unroll
    for (int i = 0; i < 8; ++i) { d[0] += wz[i] * bz[i]; d[1] += wr2[i] * br[i]; }
    block_sums<2>(d, sbuf);
    float n2z = mob_apply(wz, bz, n1z * n1z, sbz, d[0]);
    float n2r = mob_apply(wr2, br, n1r * n1r, sbr2, d[1]);

    float gz = artanh_(n2z) / n2z;
    float gr = artanh_(n2r) / n2r;
    float zz[8], v[8];
    float sv = 0.f;
    #pragma unroll
    for (int i = 0; i < 8; ++i) {
        zz[i] = sigmoid_(gz * wz[i]);
        float r = sigmoid_(gr * wr2[i]);
        v[i] = gh * hp[i] * r;            // log_map_zero(h) * r
        sv += v[i] * v[i];
    }
    store_bf8(z_out + off, zz);
    block_sums<1>(&sv, sbuf);
    float nv = sqrtf(fmaxf(sv, MINN));
    float th = fminf(tanhf(nv), MAXN);
    float cr = th / nv;
    #pragma unroll
    for (int i = 0; i < 8; ++i) v[i] *= cr;
    store_bf8(rph_bf + off, v);
    store_bf8(uxr_out + off, ur2);        // finished UxR (reused for h_tilde)
    if (t == 0) g_rph[b] = artanh_(th) / th;
}

// ---------- K6: epilogue ----------

__global__ __launch_bounds__(256) void fin_kernel(
    const u16* __restrict__ p0, const u16* __restrict__ p1,
    const u16* __restrict__ uxr, const u16* __restrict__ z_in,
    const u16* __restrict__ h_bf,
    const float* __restrict__ g_rph, const float* __restrict__ b_h,
    float* __restrict__ out) {
    __shared__ float sbuf[16];
    int b = blockIdx.x, t = threadIdx.x;
    size_t off = (size_t)b * D + t * 8;
    int cbase = t * 8;

    float wh[8], ux[8], zz[8], hp[8], bh[8], t0[8];
    load_bf8(p0 + off, wh);
    load_bf8(p1 + off, t0);
    #pragma unroll
    for (int i = 0; i < 8; ++i) wh[i] += t0[i];   // K-split partials
    load_bf8(uxr + off, ux);
    load_bf8(z_in + off, zz);
    load_bf8(h_bf + off, hp);
    load_f8(b_h + cbase, bh);

    float s[4] = {0, 0, 0, 0};
    #pragma unroll
    for (int i = 0; i < 8; ++i) {
        s[0] += wh[i] * wh[i]; s[1] += ux[i] * ux[i];
        s[2] += hp[i] * hp[i]; s[3] += bh[i] * bh[i];
    }
    block_sums<4>(s, sbuf);
    float swh = s[0], sux = s[1], shp = s[2], sbh = s[3];

    float cwh, nwh;
    mmm_finish(swh, g_rph[b], &cwh, &nwh);
    #pragma unroll
    for (int i = 0; i < 8; ++i) wh[i] *= cwh;

    // h_tilde = mob_add(mob_add(WhH, UxR), b_h)
    float d = 0.f;
    #pragma unroll
    for (int i = 0; i < 8; ++i) d += wh[i] * ux[i];
    block_sums<1>(&d, sbuf);
    float n1 = mob_apply(wh, ux, nwh * nwh, sux, d);

    d = 0.f;
    #pragma unroll
    for (int i = 0; i < 8; ++i) d += wh[i] * bh[i];
    block_sums<1>(&d, sbuf);
    float nht = mob_apply(wh, bh, n1 * n1, sbh, d);

    // minus = mob_add(-h_proj, h_tilde)
    #pragma unroll
    for (int i = 0; i < 8; ++i) ux[i] = -hp[i];   // reuse ux
    d = 0.f;
    #pragma unroll
    for (int i = 0; i < 8; ++i) d += ux[i] * wh[i];
    block_sums<1>(&d, sbuf);
    float nm = mob_apply(ux, wh, shp, nht * nht, d);

    // emz = exp_map_zero(log_map_zero(minus) * z)
    float lm = artanh_(nm) / nm;
    float sv = 0.f;
    #pragma unroll
    for (int i = 0; i < 8; ++i) {
        float v = lm * ux[i] * zz[i];
        ux[i] = v;
        sv += v * v;
    }
    block_sums<1>(&sv, sbuf);
    float nv = sqrtf(fmaxf(sv, MINN));
    float th = fminf(tanhf(nv), MAXN);
    float ce = th / nv;
    #pragma unroll
    for (int i = 0; i < 8; ++i) ux[i] *= ce;

    // new_h = mob_add(h_proj, emz)
    d = 0.f;
    #pragma unroll
    for (int i = 0; i < 8; ++i) d += hp[i] * ux[i];
    block_sums<1>(&d, sbuf);
    mob_apply(hp, ux, shp, th * th, d);
    store_f8(out + off, hp);
}

// ---------- launch ----------

extern "C" void kernel_launch(void* const* d_in, const int* in_sizes, int n_in,
                              void* d_out, int out_size, void* d_ws, size_t ws_size,
                              hipStream_t stream) {
    const float* hyp_x  = (const float*)d_in[0];
    const float* hidden = (const float*)d_in[1];
    const float* w_z = (const float*)d_in[2];
    const float* w_r = (const float*)d_in[3];
    const float* w_h = (const float*)d_in[4];
    const float* u_z = (const float*)d_in[5];
    const float* u_r = (const float*)d_in[6];
    const float* b_z = (const float*)d_in[7];
    const float* b_r = (const float*)d_in[8];
    const float* b_h = (const float*)d_in[9];
    float* out = (float*)d_out;

    int B = in_sizes[1] / D;   // 2048

    char* ws = (char*)d_ws;
    size_t o = 0;
    auto alloc = [&](size_t bytes) -> void* {
        void* p = ws + o;
        o += (bytes + 255) & ~(size_t)255;
        return p;
    };
    u16* wt[5];   // 0=w_z,1=w_r,2=w_h,3=u_z,4=u_r (transposed bf16 [N][K])
    for (int i = 0; i < 5; ++i) wt[i] = (u16*)alloc((size_t)D * D * 2);
    u16* hx_bf = (u16*)alloc((size_t)B * D * 2);
    u16* h_bf  = (u16*)alloc((size_t)B * D * 2);
    float* g_x   = (float*)alloc((size_t)B * 4);
    float* g_h   = (float*)alloc((size_t)B * 4);
    float* g_rph = (float*)alloc((size_t)B * 4);
    u16* cz0 = (u16*)alloc((size_t)B * D * 2);   // G1 outputs, bf16
    u16* cz1 = (u16*)alloc((size_t)B * D * 2);
    u16* cz2 = (u16*)alloc((size_t)B * D * 2);
    u16* cz3 = (u16*)alloc((size_t)B * D * 2);
    u16* p0 = (u16*)alloc((size_t)B * D * 2);    // G2 K-partials, bf16
    u16* p1 = (u16*)alloc((size_t)B * D * 2);
    u16* z_buf = (u16*)alloc((size_t)B * D * 2);
    u16* uxr = (u16*)alloc((size_t)B * D * 2);
    u16* rph = (u16*)alloc((size_t)B * D * 2);

    // K0: transpose the 4 G1 weights (z<4) + projection (z==4)
    PrepBatch pb;
    pb.W[0] = w_z; pb.Wt[0] = wt[0];
    pb.W[1] = w_r; pb.Wt[1] = wt[1];
    pb.W[2] = u_z; pb.Wt[2] = wt[3];
    pb.W[3] = u_r; pb.Wt[3] = wt[4];
    pb.hx = hyp_x; pb.h = hidden;
    pb.hx_bf = hx_bf; pb.h_bf = h_bf;
    pb.g_x = g_x; pb.g_h = g_h;
    wtrans_prep<<<dim3(D / 64, D / 64, 5), 256, 0, stream>>>(pb);

    // G1: z<4 GEMMs (cz0=h@w_z, cz1=x@u_z, cz2=h@w_r, cz3=x@u_r),
    //     z==4 transposes w_h (hidden under GEMM bandwidth idle time)
    G1Batch g1;
    g1.A[0] = h_bf;  g1.W[0] = wt[0]; g1.C[0] = cz0;
    g1.A[1] = hx_bf; g1.W[1] = wt[3]; g1.C[1] = cz1;
    g1.A[2] = h_bf;  g1.W[2] = wt[1]; g1.C[2] = cz2;
    g1.A[3] = hx_bf; g1.W[3] = wt[4]; g1.C[3] = cz3;
    g1.Wh = w_h; g1.WhT = wt[2];
    g1_kernel<<<dim3(D / 128, B / 128, 5), 256, 0, stream>>>(g1);

    // K4: middle fusion
    mid_kernel<<<dim3(B), 256, 0, stream>>>(cz0, cz1, cz2, cz3, h_bf, g_x, g_h,
                                            b_z, b_r, z_buf, uxr, rph, g_rph);

    // G2: 2-way K-split r_point_h @ w_h -> bf16 partials p0,p1
    GemmBatch g2;
    g2.A[0] = rph; g2.W[0] = wt[2]; g2.C[0] = p0; g2.koff[0] = 0;
    g2.A[1] = rph; g2.W[1] = wt[2]; g2.C[1] = p1; g2.koff[1] = 1024;
    g2_kernel<<<dim3(D / 128, B / 128, 2), 256, 0, stream>>>(g2);

    // K6: epilogue (sums the two K-partials of Wh @ r_point_h)
    fin_kernel<<<dim3(B), 256, 0, stream>>>(p0, p1, uxr, z_buf, h_bf,
                                            g_rph, b_h, out);
}